// Round 21
// baseline (328.083 us; speedup 1.0000x reference)
//
#include <hip/hip_runtime.h>
#include <math.h>

static constexpr int NN   = 20000;
static constexpr int TT   = 6;
static constexpr int EE   = 640000;
static constexpr int CINC = 3;
static constexpr int HH   = 64;
static constexpr int RB   = 8;    // nodes per wave (y1/head)
static constexpr int RBG  = 4;    // nodes per wave in gru6
static constexpr int BKSH = 7;    // 128 nodes per bucket
static constexpr int NBKT = (NN + (1 << BKSH) - 1) >> BKSH;  // 157
static constexpr int CAP  = 6144; // bucket capacity (expected 4096, +32 sigma)
static constexpr int EPB  = 4096; // edges per workgroup in bin phase
static constexpr int GBLK = 5000; // gather blocks per timestep (4 nodes each)

typedef __attribute__((ext_vector_type(8))) short bf16x8;
typedef __attribute__((ext_vector_type(4))) float f32x4;

// ---- bf16 helpers (storage = ushort) ------------------------------------
__device__ inline unsigned short f2bf(float f) {
    unsigned u = __float_as_uint(f);
    unsigned r = (u + 0x7FFFu + ((u >> 16) & 1u)) >> 16;  // RTNE
    return (unsigned short)r;
}
__device__ inline float bflo(unsigned u) { return __uint_as_float(u << 16); }
__device__ inline float bfhi(unsigned u) { return __uint_as_float(u & 0xFFFF0000u); }

// fast transcendentals (gru6 only)
__device__ inline float fsig(float x) {
    return __builtin_amdgcn_rcpf(1.f + __expf(-x));
}
__device__ inline float ftanh(float x) {
    x = fminf(fmaxf(x, -15.f), 15.f);
    float e = __expf(2.f * x);
    return (e - 1.f) * __builtin_amdgcn_rcpf(e + 1.f);
}

// ---- phase 1: bin edges into 157 coarse buckets (packed dstLocal|src) ----
__global__ void bin6_kernel(const int* __restrict__ edges, int* __restrict__ gcur,
                            int* __restrict__ bucketArr) {
    int t = blockIdx.y;
    __shared__ int hist[NBKT];
    __shared__ int base[NBKT];
    int tid = threadIdx.x;
    for (int i = tid; i < NBKT; i += 256) hist[i] = 0;
    __syncthreads();
    const int* src = edges + (size_t)t * 2 * EE;
    const int* dst = src + EE;
    int e0 = blockIdx.x * EPB;
    int pack[16], loff[16], bkt[16];
    int m = 0;
#pragma unroll
    for (int i = 0; i < 16; ++i) {
        int e = e0 + tid + i * 256;
        if (e < EE) {
            int s = src[e], d = dst[e];
            int b = d >> BKSH;
            bkt[i] = b;
            pack[i] = ((d & 127) << 16) | s;
            loff[i] = atomicAdd(&hist[b], 1);
            m = i + 1;
        }
    }
    __syncthreads();
    for (int i = tid; i < NBKT; i += 256)
        base[i] = atomicAdd(&gcur[t * NBKT + i], hist[i]);
    __syncthreads();
    for (int i = 0; i < m; ++i) {
        int b = bkt[i];
        int pos = base[b] + loff[i];
        if (pos < CAP)
            bucketArr[(size_t)(t * NBKT + b) * CAP + pos] = pack[i];
    }
}

// ---- tiny per-t exclusive scan of bucket counts -> bucket edge bases ----
__global__ void scan_gcur_kernel(const int* __restrict__ gcur, int* __restrict__ gbase,
                                 int* __restrict__ rowptr6) {
    int t = blockIdx.x;
    __shared__ int sv[NBKT];
    int tid = threadIdx.x;
    if (tid < NBKT) sv[tid] = gcur[t * NBKT + tid];
    __syncthreads();
    if (tid == 0) {
        int s = 0;
        for (int i = 0; i < NBKT; ++i) { int v = sv[i]; sv[i] = s; s += v; }
        rowptr6[t * (NN + 1) + NN] = EE;
    }
    __syncthreads();
    if (tid < NBKT) gbase[t * NBKT + tid] = sv[tid];
}

// ---- merged: per-bucket hist + scan -> rowptr/dinv/cursor, then regroup --
__global__ void regroup6_kernel(const int* __restrict__ gcur, const int* __restrict__ gbase,
                                const int* __restrict__ bucketArr, int* __restrict__ rowptr6,
                                float* __restrict__ dinv6, int* __restrict__ col6) {
    int bk = blockIdx.x, t = blockIdx.y;
    __shared__ int hist[128];
    __shared__ int lscan[128];
    __shared__ int cursor[128];
    __shared__ int lcol[CAP];  // 24KB
    int tid = threadIdx.x;
    if (tid < 128) hist[tid] = 0;
    __syncthreads();
    int ecnt = gcur[t * NBKT + bk];
    if (ecnt > CAP) ecnt = CAP;
    const int* barr = bucketArr + (size_t)(t * NBKT + bk) * CAP;
    for (int e = tid; e < ecnt; e += 256) atomicAdd(&hist[barr[e] >> 16], 1);
    __syncthreads();
    if (tid < 128) lscan[tid] = hist[tid];
    __syncthreads();
    for (int off = 1; off < 128; off <<= 1) {
        int v = 0, a = 0;
        if (tid < 128) { v = lscan[tid]; a = (tid >= off) ? lscan[tid - off] : 0; }
        __syncthreads();
        if (tid < 128) lscan[tid] = v + a;
        __syncthreads();
    }
    int base = gbase[t * NBKT + bk];
    int nb0 = bk << BKSH;
    if (tid < 128) {
        int excl = lscan[tid] - hist[tid];
        cursor[tid] = excl;
        int n = nb0 + tid;
        if (n < NN) {
            rowptr6[t * (NN + 1) + n] = base + excl;
            dinv6[t * NN + n] = rsqrtf((float)hist[tid] + 1.0f);
        }
    }
    __syncthreads();
    for (int e = tid; e < ecnt; e += 256) {
        int w = barr[e];
        int dl = w >> 16, s = w & 0xFFFF;
        int off = atomicAdd(&cursor[dl], 1);
        lcol[off] = s;
    }
    __syncthreads();
    int* colt = col6 + (size_t)t * EE + base;
    for (int e = tid; e < ecnt; e += 256) colt[e] = lcol[e];
}

// ---- hidden-side GRU weight repack (bf16) for gru6 ----------------------
__global__ void pack_gruh_kernel(const float* __restrict__ whh,
                                 unsigned* __restrict__ Wh01, unsigned short* __restrict__ Whn) {
    int idx = blockIdx.x * blockDim.x + threadIdx.x;  // k*64 + jj
    if (idx >= HH * HH) return;
    int k = idx >> 6, jj = idx & 63;
    unsigned w_hr = f2bf(whh[jj * HH + k]);
    unsigned w_hz = f2bf(whh[(64 + jj) * HH + k]);
    unsigned w_hn = f2bf(whh[(128 + jj) * HH + k]);
    Wh01[idx] = w_hr | (w_hz << 16);
    Whn[idx] = (unsigned short)w_hn;
}

// ---- MFMA B-fragment pack (wih, 24 frags) -------------------------------
__global__ void pack_bfrag_kernel(const float* __restrict__ wih,
                                  unsigned short* __restrict__ Bfrag) {
    int idx = blockIdx.x * blockDim.x + threadIdx.x;
    if (idx >= 24 * 64 * 8) return;
    int frag = idx >> 9;
    int l    = (idx >> 3) & 63;
    int e    = idx & 7;
    int jt = frag >> 1, kk = frag & 1;
    int j = jt * 16 + (l & 15);
    int k = kk * 32 + ((l >> 4) << 3) + e;
    Bfrag[idx] = f2bf(wih[j * HH + k]);
}

// ---- MFMA B-fragment pack (W2, 8 frags): B[k][j] = W2[k*HH+j] -----------
__global__ void pack_bfrag2_kernel(const float* __restrict__ W2,
                                   unsigned short* __restrict__ Bfrag2) {
    int idx = blockIdx.x * blockDim.x + threadIdx.x;
    if (idx >= 8 * 64 * 8) return;
    int frag = idx >> 9;
    int l    = (idx >> 3) & 63;
    int e    = idx & 7;
    int jt = frag >> 1, kk = frag & 1;
    int j = jt * 16 + (l & 15);
    int k = kk * 32 + ((l >> 4) << 3) + e;
    Bfrag2[idx] = f2bf(W2[k * HH + j]);
}

// ---- y1 for ALL t: y = dinv * (x @ W1), bf16 out ------------------------
__global__ void y1all_kernel(const float* __restrict__ nf, const float* __restrict__ W1,
                             const float* __restrict__ dinv6, unsigned short* __restrict__ Yb) {
    int t = blockIdx.y;
    int gid = blockIdx.x * blockDim.x + threadIdx.x;
    if (gid >= NN * HH) return;
    int node = gid >> 6, hh = gid & 63;
    const float* xr = nf + (size_t)t * NN * CINC + node * CINC;
    float acc = 0.f;
#pragma unroll
    for (int k = 0; k < CINC; ++k) acc = fmaf(xr[k], W1[k * HH + hh], acc);
    Yb[(size_t)t * NN * HH + gid] = f2bf(dinv6[t * NN + node] * acc);
}

// ---- y2 via MFMA: Y2[m][j] = dinv6[m] * (Zb1 @ W2)[m][j] ----------------
__global__ __launch_bounds__(256) void y2all_mfma_kernel(
        const unsigned short* __restrict__ Zb1, const unsigned short* __restrict__ Bfrag2,
        const float* __restrict__ dinv6, unsigned short* __restrict__ Y2all) {
    int w = threadIdx.x >> 6, lane = threadIdx.x & 63;
    int tile = blockIdx.x * 4 + w;
    int m0 = tile << 4;
    int r16 = lane & 15, kg = lane >> 4;
    const unsigned short* zrow = Zb1 + ((size_t)(m0 + r16) << 6) + (kg << 3);
    bf16x8 a0 = *(const bf16x8*)zrow;
    bf16x8 a1 = *(const bf16x8*)(zrow + 32);
    f32x4 acc[4];
#pragma unroll
    for (int jt = 0; jt < 4; ++jt) {
        bf16x8 b0 = *(const bf16x8*)(Bfrag2 + ((size_t)((jt << 1) + 0) << 9) + (lane << 3));
        bf16x8 b1 = *(const bf16x8*)(Bfrag2 + ((size_t)((jt << 1) + 1) << 9) + (lane << 3));
        f32x4 c = {0.f, 0.f, 0.f, 0.f};
        c = __builtin_amdgcn_mfma_f32_16x16x32_bf16(a0, b0, c, 0, 0, 0);
        c = __builtin_amdgcn_mfma_f32_16x16x32_bf16(a1, b1, c, 0, 0, 0);
        acc[jt] = c;
    }
#pragma unroll
    for (int jt = 0; jt < 4; ++jt) {
#pragma unroll
        for (int reg = 0; reg < 4; ++reg) {
            int m = m0 + (kg << 2) + reg;
            Y2all[((size_t)m << 6) + jt * 16 + r16] = f2bf(acc[jt][reg] * dinv6[m]);
        }
    }
}

// ---- CSR gather, XCD-partitioned: each timestep pinned to its own XCD ----
// 1D grid of 8*GBLK blocks; xcd = bid&7 (round-robin dispatch assumption):
//   xcd 0: t0 blocks [0,2500)    xcd 6: t0 blocks [2500,5000)
//   xcd 1: t1 blocks [0,2500)    xcd 7: t1 blocks [2500,5000)
//   xcd 2..5: t2..5 blocks [0,5000)
__global__ void gather6_kernel(const int* __restrict__ rowptr6, const int* __restrict__ col6,
                               const float* __restrict__ dinv6, const unsigned short* __restrict__ ybase,
                               const float* __restrict__ b, unsigned short* __restrict__ zbase) {
    int bid = blockIdx.x;
    int xcd = bid & 7;
    int i = bid >> 3;
    int t, iblk;
    if (xcd < 2) {            // t0/t1 first half
        if (i >= GBLK / 2) return;
        t = xcd; iblk = i;
    } else if (xcd < 6) {     // t2..t5 full
        t = xcd; iblk = i;
    } else {                  // t0/t1 second half
        if (i >= GBLK / 2) return;
        t = xcd - 6; iblk = i + GBLK / 2;
    }
    const int* rowptr = rowptr6 + t * (NN + 1);
    const int* col = col6 + (size_t)t * EE;
    const float* dinv = dinv6 + t * NN;
    const unsigned char* y = (const unsigned char*)(ybase + (size_t)t * NN * HH);
    unsigned short* z = zbase + (size_t)t * NN * HH;

    int node = (iblk * 256 + threadIdx.x) >> 6;
    if (node >= NN) return;
    int lane = threadIdx.x & 63;
    int g = lane >> 3, q = lane & 7;
    int ps = rowptr[node], pe = rowptr[node + 1];
    unsigned qoff = (unsigned)q << 4;
    float acc[8];
    if (g == 0) {  // self term
        const uint4 v = *(const uint4*)(y + (((unsigned)node << 7) + qoff));
        acc[0] = bflo(v.x); acc[1] = bfhi(v.x);
        acc[2] = bflo(v.y); acc[3] = bfhi(v.y);
        acc[4] = bflo(v.z); acc[5] = bfhi(v.z);
        acc[6] = bflo(v.w); acc[7] = bfhi(v.w);
    } else {
#pragma unroll
        for (int j = 0; j < 8; ++j) acc[j] = 0.f;
    }
    for (int p = ps + g; p < pe; p += 8) {
        unsigned c = (unsigned)col[p];
        const uint4 v = *(const uint4*)(y + ((c << 7) + qoff));
        acc[0] += bflo(v.x); acc[1] += bfhi(v.x);
        acc[2] += bflo(v.y); acc[3] += bfhi(v.y);
        acc[4] += bflo(v.z); acc[5] += bfhi(v.z);
        acc[6] += bflo(v.w); acc[7] += bfhi(v.w);
    }
#pragma unroll
    for (int j = 0; j < 8; ++j) {
        acc[j] += __shfl_xor(acc[j], 8);
        acc[j] += __shfl_xor(acc[j], 16);
        acc[j] += __shfl_xor(acc[j], 32);
    }
    if (g == 0) {
        float d = dinv[node];
        const float4 b0 = *(const float4*)(b + (q << 3));
        const float4 b1 = *(const float4*)(b + (q << 3) + 4);
        float o[8];
        o[0] = fmaf(d, acc[0], b0.x); o[1] = fmaf(d, acc[1], b0.y);
        o[2] = fmaf(d, acc[2], b0.z); o[3] = fmaf(d, acc[3], b0.w);
        o[4] = fmaf(d, acc[4], b1.x); o[5] = fmaf(d, acc[5], b1.y);
        o[6] = fmaf(d, acc[6], b1.z); o[7] = fmaf(d, acc[7], b1.w);
#pragma unroll
        for (int j = 0; j < 8; ++j) o[j] = o[j] > 0.f ? o[j] : 0.f;
        uint4 w;
        w.x = (unsigned)f2bf(o[0]) | ((unsigned)f2bf(o[1]) << 16);
        w.y = (unsigned)f2bf(o[2]) | ((unsigned)f2bf(o[3]) << 16);
        w.z = (unsigned)f2bf(o[4]) | ((unsigned)f2bf(o[5]) << 16);
        w.w = (unsigned)f2bf(o[6]) | ((unsigned)f2bf(o[7]) << 16);
        *(uint4*)(z + ((size_t)node << 6) + (q << 3)) = w;
    }
}

// ---- gi via MFMA: gi[m][j] = (Zb2 @ wihT)[m][j] + bih[j] ----------------
__global__ __launch_bounds__(256) void giall_mfma_kernel(
        const unsigned short* __restrict__ Zb6, const unsigned short* __restrict__ Bfrag,
        const float* __restrict__ bih, unsigned short* __restrict__ gi) {
    int w = threadIdx.x >> 6, lane = threadIdx.x & 63;
    int tile = blockIdx.x * 4 + w;
    int m0 = tile << 4;
    int r16 = lane & 15, kg = lane >> 4;
    const unsigned short* zrow = Zb6 + ((size_t)(m0 + r16) << 6) + (kg << 3);
    bf16x8 a0 = *(const bf16x8*)zrow;
    bf16x8 a1 = *(const bf16x8*)(zrow + 32);
    f32x4 acc[12];
#pragma unroll
    for (int jt = 0; jt < 12; ++jt) {
        bf16x8 b0 = *(const bf16x8*)(Bfrag + ((size_t)((jt << 1) + 0) << 9) + (lane << 3));
        bf16x8 b1 = *(const bf16x8*)(Bfrag + ((size_t)((jt << 1) + 1) << 9) + (lane << 3));
        f32x4 c = {0.f, 0.f, 0.f, 0.f};
        c = __builtin_amdgcn_mfma_f32_16x16x32_bf16(a0, b0, c, 0, 0, 0);
        c = __builtin_amdgcn_mfma_f32_16x16x32_bf16(a1, b1, c, 0, 0, 0);
        acc[jt] = c;
    }
#pragma unroll
    for (int jt = 0; jt < 12; ++jt) {
        float bi = bih[jt * 16 + r16];
#pragma unroll
        for (int reg = 0; reg < 4; ++reg) {
            int node = m0 + (kg << 2) + reg;
            gi[(size_t)node * 192 + jt * 16 + r16] = f2bf(acc[jt][reg] + bi);
        }
    }
}

// ---- fused 6-step GRU v6: RBG=4 nodes/wave, 4 waves/block (5000 waves) --
__global__ __launch_bounds__(256) void gru6_kernel(
        const unsigned short* __restrict__ gi,
        const unsigned* __restrict__ Wh01, const unsigned short* __restrict__ Whn,
        const float* __restrict__ bhh, float* __restrict__ hfinal) {
    __shared__ unsigned sW01[HH * HH];        // 16 KB
    __shared__ unsigned short sWn[HH * HH];   // 8 KB
    __shared__ float hs[4][RBG][HH];          // 4 KB
    int tid = threadIdx.x;
    int wid = tid >> 6, lane = tid & 63;
    int nbase = (blockIdx.x * 4 + wid) * RBG;

    for (int i = tid; i < HH * HH; i += 256) { sW01[i] = Wh01[i]; sWn[i] = Whn[i]; }
    __syncthreads();

#pragma unroll
    for (int r = 0; r < RBG; ++r) hs[wid][r][lane] = 0.f;
    float bh0 = bhh[lane], bh1 = bhh[64 + lane], bh2 = bhh[128 + lane];

#pragma unroll 1
    for (int t = 0; t < TT; ++t) {
        float aR[RBG], aZ[RBG], aN[RBG];
#pragma unroll
        for (int r = 0; r < RBG; ++r) { aR[r] = aZ[r] = aN[r] = 0.f; }
#pragma unroll 1
        for (int k0 = 0; k0 < 16; ++k0) {
            float4 hv[RBG];
#pragma unroll
            for (int r = 0; r < RBG; ++r) hv[r] = *(const float4*)(&hs[wid][r][k0 << 2]);
#pragma unroll
            for (int u = 0; u < 4; ++u) {
                int k = k0 * 4 + u;
                unsigned w01 = sW01[(k << 6) + lane];
                float w_hr = bflo(w01), w_hz = bfhi(w01);
                float w_hn = bflo((unsigned)sWn[(k << 6) + lane]);
#pragma unroll
                for (int r = 0; r < RBG; ++r) {
                    float hk = (u == 0) ? hv[r].x : (u == 1) ? hv[r].y
                             : (u == 2) ? hv[r].z : hv[r].w;
                    aR[r] = fmaf(hk, w_hr, aR[r]);
                    aZ[r] = fmaf(hk, w_hz, aZ[r]);
                    aN[r] = fmaf(hk, w_hn, aN[r]);
                }
            }
        }
        const unsigned short* gp = gi + ((size_t)t * NN + nbase) * 192;
#pragma unroll
        for (int r = 0; r < RBG; ++r) {
            size_t gb = (size_t)r * 192;
            float gr = bflo((unsigned)gp[gb + lane]);
            float gz = bflo((unsigned)gp[gb + 64 + lane]);
            float gn = bflo((unsigned)gp[gb + 128 + lane]);
            float rr = fsig(gr + aR[r] + bh0);
            float zz = fsig(gz + aZ[r] + bh1);
            float nn_ = ftanh(gn + rr * (aN[r] + bh2));
            hs[wid][r][lane] = (1.f - zz) * nn_ + zz * hs[wid][r][lane];
        }
    }
#pragma unroll
    for (int r = 0; r < RBG; ++r)
        hfinal[((size_t)(nbase + r) << 6) + lane] = hs[wid][r][lane];
}

// ---- fused MLP head: out = sigmoid(relu(h@W3+b3)@W4 + b4) ---------------
__global__ void head_kernel(const float* __restrict__ h, const float* __restrict__ W3,
                            const float* __restrict__ b3, const float* __restrict__ W4,
                            const float* __restrict__ b4, float* __restrict__ out) {
    int nbase = blockIdx.x * RB;
    int lane = threadIdx.x;
    float acc[RB];
#pragma unroll
    for (int r = 0; r < RB; ++r) acc[r] = 0.f;
    for (int k0 = 0; k0 < 16; ++k0) {
        float4 hv[RB];
#pragma unroll
        for (int r = 0; r < RB; ++r)
            hv[r] = ((const float4*)(h + ((size_t)(nbase + r) << 6)))[k0];
#pragma unroll
        for (int u = 0; u < 4; ++u) {
            float w = W3[(k0 * 4 + u) * HH + lane];
#pragma unroll
            for (int r = 0; r < RB; ++r) {
                float hk = (u == 0) ? hv[r].x : (u == 1) ? hv[r].y : (u == 2) ? hv[r].z : hv[r].w;
                acc[r] = fmaf(hk, w, acc[r]);
            }
        }
    }
    float bb = b3[lane], w4 = W4[lane], b40 = b4[0];
#pragma unroll
    for (int r = 0; r < RB; ++r) {
        float v = acc[r] + bb;
        v = v > 0.f ? v : 0.f;
        float s = v * w4;
        s += __shfl_xor(s, 32); s += __shfl_xor(s, 16); s += __shfl_xor(s, 8);
        s += __shfl_xor(s, 4);  s += __shfl_xor(s, 2);  s += __shfl_xor(s, 1);
        if (lane == r) out[nbase + r] = 1.f / (1.f + expf(-(s + b40)));
    }
}

extern "C" void kernel_launch(void* const* d_in, const int* in_sizes, int n_in,
                              void* d_out, int out_size, void* d_ws, size_t ws_size,
                              hipStream_t stream) {
    const float* nf    = (const float*)d_in[0];
    const int*   edges = (const int*)  d_in[1];
    const float* W1  = (const float*)d_in[2];
    const float* b1  = (const float*)d_in[3];
    const float* W2  = (const float*)d_in[4];
    const float* b2  = (const float*)d_in[5];
    const float* wih = (const float*)d_in[6];
    const float* whh = (const float*)d_in[7];
    const float* bih = (const float*)d_in[8];
    const float* bhh = (const float*)d_in[9];
    const float* W3  = (const float*)d_in[10];
    const float* b3  = (const float*)d_in[11];
    const float* W4  = (const float*)d_in[12];
    const float* b4  = (const float*)d_in[13];
    float* out = (float*)d_out;

    // workspace layout
    int* wsi      = (int*)d_ws;
    int* gcur     = wsi;                              // 6*NBKT (zeroed)
    int* gbase    = gcur + 6 * NBKT;                  // 6*NBKT
    int* rowptr6  = gbase + 6 * NBKT;                 // 6*(NN+1)
    int* col6     = rowptr6 + 6 * (NN + 1);           // 6*EE
    int* bucketArr= col6 + (size_t)6 * EE;            // 6*NBKT*CAP
    uintptr_t fbase = ((uintptr_t)(bucketArr + (size_t)6 * NBKT * CAP) + 15) & ~(uintptr_t)15;
    unsigned short* Bfrag = (unsigned short*)fbase;   // 24*64*8 bf16
    unsigned short* Bfrag2= Bfrag + 24 * 64 * 8;      // 8*64*8 bf16
    unsigned* Wh01= (unsigned*)(Bfrag2 + 8 * 64 * 8); // 4096 uint
    unsigned short* Whn = (unsigned short*)(Wh01 + HH * HH);  // 4096 ushort
    float* dinv6 = (float*)(Whn + HH * HH);           // 6*NN
    float* Hf    = dinv6 + 6 * NN;                    // NN*HH (final h, fp32)
    unsigned short* Yb    = (unsigned short*)(Hf + (size_t)NN * HH);  // 6*NN*HH bf16
    unsigned short* Y2all = Yb + (size_t)6 * NN * HH;                 // 6*NN*HH bf16
    unsigned short* Zb1   = Y2all + (size_t)6 * NN * HH;              // 6*NN*HH bf16
    unsigned short* Zb2   = Zb1 + (size_t)6 * NN * HH;                // 6*NN*HH bf16
    unsigned short* gi    = Zb2 + (size_t)6 * NN * HH;                // 6*NN*192 bf16

    const int BS  = 256;
    const int gNH = (NN * HH + BS - 1) / BS;   // 5000
    const int gRB = NN / RB;                   // 2500
    const int gG6 = NN / (RBG * 4);            // 1250 blocks x 4 waves
    const int gMM = (TT * NN) / 64;            // 1875
    const int gBIN = (EE + EPB - 1) / EPB;     // 157
    const int gGA = 8 * GBLK;                  // 40000 (XCD-partitioned gather)

    hipMemsetAsync(gcur, 0, 6 * NBKT * sizeof(int), stream);
    pack_gruh_kernel<<<(HH * HH + BS - 1) / BS, BS, 0, stream>>>(whh, Wh01, Whn);
    pack_bfrag_kernel<<<(24 * 64 * 8 + BS - 1) / BS, BS, 0, stream>>>(wih, Bfrag);
    pack_bfrag2_kernel<<<(8 * 64 * 8 + BS - 1) / BS, BS, 0, stream>>>(W2, Bfrag2);

    bin6_kernel<<<dim3(gBIN, TT), BS, 0, stream>>>(edges, gcur, bucketArr);
    scan_gcur_kernel<<<TT, BS, 0, stream>>>(gcur, gbase, rowptr6);
    regroup6_kernel<<<dim3(NBKT, TT), BS, 0, stream>>>(gcur, gbase, bucketArr,
                                                       rowptr6, dinv6, col6);
    y1all_kernel<<<dim3(gNH, TT), BS, 0, stream>>>(nf, W1, dinv6, Yb);

    // GCN layer 1 (all t) -> dense via MFMA (all t) -> GCN layer 2 (all t)
    gather6_kernel<<<gGA, BS, 0, stream>>>(rowptr6, col6, dinv6, Yb, b1, Zb1);
    y2all_mfma_kernel<<<gMM, 256, 0, stream>>>(Zb1, Bfrag2, dinv6, Y2all);
    gather6_kernel<<<gGA, BS, 0, stream>>>(rowptr6, col6, dinv6, Y2all, b2, Zb2);

    // gi = Zb2 @ wihT + bih via MFMA, then sequential h-only GRU
    giall_mfma_kernel<<<gMM, 256, 0, stream>>>(Zb2, Bfrag, bih, gi);
    gru6_kernel<<<gG6, 256, 0, stream>>>(gi, Wh01, Whn, bhh, Hf);

    head_kernel<<<gRB, 64, 0, stream>>>(Hf, W3, b3, W4, b4, out);
}

// Round 23
// 293.577 us; speedup vs baseline: 1.1175x; 1.1175x over previous
//
#include <hip/hip_runtime.h>
#include <math.h>

static constexpr int NN   = 20000;
static constexpr int TT   = 6;
static constexpr int EE   = 640000;
static constexpr int CINC = 3;
static constexpr int HH   = 64;
static constexpr int RB   = 8;    // nodes per wave (y1/head)
static constexpr int RBG  = 4;    // nodes per wave in gru6
static constexpr int BKSH = 7;    // 128 nodes per bucket
static constexpr int NBKT = (NN + (1 << BKSH) - 1) >> BKSH;  // 157
static constexpr int CAP  = 6144; // bucket capacity (expected 4096, +32 sigma)
static constexpr int EPB  = 4096; // edges per workgroup in bin phase
static constexpr int GBLK = 5000; // gather blocks per timestep (4 nodes each)
static constexpr int GTOT = TT * GBLK;      // 30000 gather work items
static constexpr int GPX  = GTOT / 8;       // 3750 per XCD (balanced)

typedef __attribute__((ext_vector_type(8))) short bf16x8;
typedef __attribute__((ext_vector_type(4))) float f32x4;

// ---- bf16 helpers (storage = ushort) ------------------------------------
__device__ inline unsigned short f2bf(float f) {
    unsigned u = __float_as_uint(f);
    unsigned r = (u + 0x7FFFu + ((u >> 16) & 1u)) >> 16;  // RTNE
    return (unsigned short)r;
}
__device__ inline float bflo(unsigned u) { return __uint_as_float(u << 16); }
__device__ inline float bfhi(unsigned u) { return __uint_as_float(u & 0xFFFF0000u); }

// fast transcendentals (gru6 only)
__device__ inline float fsig(float x) {
    return __builtin_amdgcn_rcpf(1.f + __expf(-x));
}
__device__ inline float ftanh(float x) {
    x = fminf(fmaxf(x, -15.f), 15.f);
    float e = __expf(2.f * x);
    return (e - 1.f) * __builtin_amdgcn_rcpf(e + 1.f);
}

// ---- phase 1: bin edges into 157 coarse buckets (packed dstLocal|src) ----
__global__ void bin6_kernel(const int* __restrict__ edges, int* __restrict__ gcur,
                            int* __restrict__ bucketArr) {
    int t = blockIdx.y;
    __shared__ int hist[NBKT];
    __shared__ int base[NBKT];
    int tid = threadIdx.x;
    for (int i = tid; i < NBKT; i += 256) hist[i] = 0;
    __syncthreads();
    const int* src = edges + (size_t)t * 2 * EE;
    const int* dst = src + EE;
    int e0 = blockIdx.x * EPB;
    int pack[16], loff[16], bkt[16];
    int m = 0;
#pragma unroll
    for (int i = 0; i < 16; ++i) {
        int e = e0 + tid + i * 256;
        if (e < EE) {
            int s = src[e], d = dst[e];
            int b = d >> BKSH;
            bkt[i] = b;
            pack[i] = ((d & 127) << 16) | s;
            loff[i] = atomicAdd(&hist[b], 1);
            m = i + 1;
        }
    }
    __syncthreads();
    for (int i = tid; i < NBKT; i += 256)
        base[i] = atomicAdd(&gcur[t * NBKT + i], hist[i]);
    __syncthreads();
    for (int i = 0; i < m; ++i) {
        int b = bkt[i];
        int pos = base[b] + loff[i];
        if (pos < CAP)
            bucketArr[(size_t)(t * NBKT + b) * CAP + pos] = pack[i];
    }
}

// ---- tiny per-t exclusive scan of bucket counts -> bucket edge bases ----
__global__ void scan_gcur_kernel(const int* __restrict__ gcur, int* __restrict__ gbase,
                                 int* __restrict__ rowptr6) {
    int t = blockIdx.x;
    __shared__ int sv[NBKT];
    int tid = threadIdx.x;
    if (tid < NBKT) sv[tid] = gcur[t * NBKT + tid];
    __syncthreads();
    if (tid == 0) {
        int s = 0;
        for (int i = 0; i < NBKT; ++i) { int v = sv[i]; sv[i] = s; s += v; }
        rowptr6[t * (NN + 1) + NN] = EE;
    }
    __syncthreads();
    if (tid < NBKT) gbase[t * NBKT + tid] = sv[tid];
}

// ---- merged: per-bucket hist + scan -> rowptr/dinv/cursor, then regroup --
__global__ void regroup6_kernel(const int* __restrict__ gcur, const int* __restrict__ gbase,
                                const int* __restrict__ bucketArr, int* __restrict__ rowptr6,
                                float* __restrict__ dinv6, int* __restrict__ col6) {
    int bk = blockIdx.x, t = blockIdx.y;
    __shared__ int hist[128];
    __shared__ int lscan[128];
    __shared__ int cursor[128];
    __shared__ int lcol[CAP];  // 24KB
    int tid = threadIdx.x;
    if (tid < 128) hist[tid] = 0;
    __syncthreads();
    int ecnt = gcur[t * NBKT + bk];
    if (ecnt > CAP) ecnt = CAP;
    const int* barr = bucketArr + (size_t)(t * NBKT + bk) * CAP;
    for (int e = tid; e < ecnt; e += 256) atomicAdd(&hist[barr[e] >> 16], 1);
    __syncthreads();
    if (tid < 128) lscan[tid] = hist[tid];
    __syncthreads();
    for (int off = 1; off < 128; off <<= 1) {
        int v = 0, a = 0;
        if (tid < 128) { v = lscan[tid]; a = (tid >= off) ? lscan[tid - off] : 0; }
        __syncthreads();
        if (tid < 128) lscan[tid] = v + a;
        __syncthreads();
    }
    int base = gbase[t * NBKT + bk];
    int nb0 = bk << BKSH;
    if (tid < 128) {
        int excl = lscan[tid] - hist[tid];
        cursor[tid] = excl;
        int n = nb0 + tid;
        if (n < NN) {
            rowptr6[t * (NN + 1) + n] = base + excl;
            dinv6[t * NN + n] = rsqrtf((float)hist[tid] + 1.0f);
        }
    }
    __syncthreads();
    for (int e = tid; e < ecnt; e += 256) {
        int w = barr[e];
        int dl = w >> 16, s = w & 0xFFFF;
        int off = atomicAdd(&cursor[dl], 1);
        lcol[off] = s;
    }
    __syncthreads();
    int* colt = col6 + (size_t)t * EE + base;
    for (int e = tid; e < ecnt; e += 256) colt[e] = lcol[e];
}

// ---- hidden-side GRU weight repack (bf16) for gru6 ----------------------
__global__ void pack_gruh_kernel(const float* __restrict__ whh,
                                 unsigned* __restrict__ Wh01, unsigned short* __restrict__ Whn) {
    int idx = blockIdx.x * blockDim.x + threadIdx.x;  // k*64 + jj
    if (idx >= HH * HH) return;
    int k = idx >> 6, jj = idx & 63;
    unsigned w_hr = f2bf(whh[jj * HH + k]);
    unsigned w_hz = f2bf(whh[(64 + jj) * HH + k]);
    unsigned w_hn = f2bf(whh[(128 + jj) * HH + k]);
    Wh01[idx] = w_hr | (w_hz << 16);
    Whn[idx] = (unsigned short)w_hn;
}

// ---- MFMA B-fragment pack (wih, 24 frags) -------------------------------
__global__ void pack_bfrag_kernel(const float* __restrict__ wih,
                                  unsigned short* __restrict__ Bfrag) {
    int idx = blockIdx.x * blockDim.x + threadIdx.x;
    if (idx >= 24 * 64 * 8) return;
    int frag = idx >> 9;
    int l    = (idx >> 3) & 63;
    int e    = idx & 7;
    int jt = frag >> 1, kk = frag & 1;
    int j = jt * 16 + (l & 15);
    int k = kk * 32 + ((l >> 4) << 3) + e;
    Bfrag[idx] = f2bf(wih[j * HH + k]);
}

// ---- MFMA B-fragment pack (W2, 8 frags): B[k][j] = W2[k*HH+j] -----------
__global__ void pack_bfrag2_kernel(const float* __restrict__ W2,
                                   unsigned short* __restrict__ Bfrag2) {
    int idx = blockIdx.x * blockDim.x + threadIdx.x;
    if (idx >= 8 * 64 * 8) return;
    int frag = idx >> 9;
    int l    = (idx >> 3) & 63;
    int e    = idx & 7;
    int jt = frag >> 1, kk = frag & 1;
    int j = jt * 16 + (l & 15);
    int k = kk * 32 + ((l >> 4) << 3) + e;
    Bfrag2[idx] = f2bf(W2[k * HH + j]);
}

// ---- y1 for ALL t: y = dinv * (x @ W1), bf16 out ------------------------
__global__ void y1all_kernel(const float* __restrict__ nf, const float* __restrict__ W1,
                             const float* __restrict__ dinv6, unsigned short* __restrict__ Yb) {
    int t = blockIdx.y;
    int gid = blockIdx.x * blockDim.x + threadIdx.x;
    if (gid >= NN * HH) return;
    int node = gid >> 6, hh = gid & 63;
    const float* xr = nf + (size_t)t * NN * CINC + node * CINC;
    float acc = 0.f;
#pragma unroll
    for (int k = 0; k < CINC; ++k) acc = fmaf(xr[k], W1[k * HH + hh], acc);
    Yb[(size_t)t * NN * HH + gid] = f2bf(dinv6[t * NN + node] * acc);
}

// ---- y2 via MFMA: Y2[m][j] = dinv6[m] * (Zb1 @ W2)[m][j] ----------------
__global__ __launch_bounds__(256) void y2all_mfma_kernel(
        const unsigned short* __restrict__ Zb1, const unsigned short* __restrict__ Bfrag2,
        const float* __restrict__ dinv6, unsigned short* __restrict__ Y2all) {
    int w = threadIdx.x >> 6, lane = threadIdx.x & 63;
    int tile = blockIdx.x * 4 + w;
    int m0 = tile << 4;
    int r16 = lane & 15, kg = lane >> 4;
    const unsigned short* zrow = Zb1 + ((size_t)(m0 + r16) << 6) + (kg << 3);
    bf16x8 a0 = *(const bf16x8*)zrow;
    bf16x8 a1 = *(const bf16x8*)(zrow + 32);
    f32x4 acc[4];
#pragma unroll
    for (int jt = 0; jt < 4; ++jt) {
        bf16x8 b0 = *(const bf16x8*)(Bfrag2 + ((size_t)((jt << 1) + 0) << 9) + (lane << 3));
        bf16x8 b1 = *(const bf16x8*)(Bfrag2 + ((size_t)((jt << 1) + 1) << 9) + (lane << 3));
        f32x4 c = {0.f, 0.f, 0.f, 0.f};
        c = __builtin_amdgcn_mfma_f32_16x16x32_bf16(a0, b0, c, 0, 0, 0);
        c = __builtin_amdgcn_mfma_f32_16x16x32_bf16(a1, b1, c, 0, 0, 0);
        acc[jt] = c;
    }
#pragma unroll
    for (int jt = 0; jt < 4; ++jt) {
#pragma unroll
        for (int reg = 0; reg < 4; ++reg) {
            int m = m0 + (kg << 2) + reg;
            Y2all[((size_t)m << 6) + jt * 16 + r16] = f2bf(acc[jt][reg] * dinv6[m]);
        }
    }
}

// ---- CSR gather, balanced XCD partition ---------------------------------
// 1D grid of GTOT blocks; xcd = bid&7 gets contiguous work [xcd*GPX, +GPX)
// from the t-major ordering -> each XCD touches <=2 adjacent t-slices.
__global__ void gather6_kernel(const int* __restrict__ rowptr6, const int* __restrict__ col6,
                               const float* __restrict__ dinv6, const unsigned short* __restrict__ ybase,
                               const float* __restrict__ b, unsigned short* __restrict__ zbase) {
    int bid = blockIdx.x;
    int widx = (bid & 7) * GPX + (bid >> 3);   // balanced, contiguous per XCD
    int t = widx / GBLK;
    int iblk = widx - t * GBLK;
    const int* rowptr = rowptr6 + t * (NN + 1);
    const int* col = col6 + (size_t)t * EE;
    const float* dinv = dinv6 + t * NN;
    const unsigned char* y = (const unsigned char*)(ybase + (size_t)t * NN * HH);
    unsigned short* z = zbase + (size_t)t * NN * HH;

    int node = (iblk * 256 + threadIdx.x) >> 6;
    if (node >= NN) return;
    int lane = threadIdx.x & 63;
    int g = lane >> 3, q = lane & 7;
    int ps = rowptr[node], pe = rowptr[node + 1];
    unsigned qoff = (unsigned)q << 4;
    float acc[8];
    if (g == 0) {  // self term
        const uint4 v = *(const uint4*)(y + (((unsigned)node << 7) + qoff));
        acc[0] = bflo(v.x); acc[1] = bfhi(v.x);
        acc[2] = bflo(v.y); acc[3] = bfhi(v.y);
        acc[4] = bflo(v.z); acc[5] = bfhi(v.z);
        acc[6] = bflo(v.w); acc[7] = bfhi(v.w);
    } else {
#pragma unroll
        for (int j = 0; j < 8; ++j) acc[j] = 0.f;
    }
    for (int p = ps + g; p < pe; p += 8) {
        unsigned c = (unsigned)col[p];
        const uint4 v = *(const uint4*)(y + ((c << 7) + qoff));
        acc[0] += bflo(v.x); acc[1] += bfhi(v.x);
        acc[2] += bflo(v.y); acc[3] += bfhi(v.y);
        acc[4] += bflo(v.z); acc[5] += bfhi(v.z);
        acc[6] += bflo(v.w); acc[7] += bfhi(v.w);
    }
#pragma unroll
    for (int j = 0; j < 8; ++j) {
        acc[j] += __shfl_xor(acc[j], 8);
        acc[j] += __shfl_xor(acc[j], 16);
        acc[j] += __shfl_xor(acc[j], 32);
    }
    if (g == 0) {
        float d = dinv[node];
        const float4 b0 = *(const float4*)(b + (q << 3));
        const float4 b1 = *(const float4*)(b + (q << 3) + 4);
        float o[8];
        o[0] = fmaf(d, acc[0], b0.x); o[1] = fmaf(d, acc[1], b0.y);
        o[2] = fmaf(d, acc[2], b0.z); o[3] = fmaf(d, acc[3], b0.w);
        o[4] = fmaf(d, acc[4], b1.x); o[5] = fmaf(d, acc[5], b1.y);
        o[6] = fmaf(d, acc[6], b1.z); o[7] = fmaf(d, acc[7], b1.w);
#pragma unroll
        for (int j = 0; j < 8; ++j) o[j] = o[j] > 0.f ? o[j] : 0.f;
        uint4 w;
        w.x = (unsigned)f2bf(o[0]) | ((unsigned)f2bf(o[1]) << 16);
        w.y = (unsigned)f2bf(o[2]) | ((unsigned)f2bf(o[3]) << 16);
        w.z = (unsigned)f2bf(o[4]) | ((unsigned)f2bf(o[5]) << 16);
        w.w = (unsigned)f2bf(o[6]) | ((unsigned)f2bf(o[7]) << 16);
        *(uint4*)(z + ((size_t)node << 6) + (q << 3)) = w;
    }
}

// ---- gi via MFMA: gi[m][j] = (Zb2 @ wihT)[m][j] + bih[j] ----------------
__global__ __launch_bounds__(256) void giall_mfma_kernel(
        const unsigned short* __restrict__ Zb6, const unsigned short* __restrict__ Bfrag,
        const float* __restrict__ bih, unsigned short* __restrict__ gi) {
    int w = threadIdx.x >> 6, lane = threadIdx.x & 63;
    int tile = blockIdx.x * 4 + w;
    int m0 = tile << 4;
    int r16 = lane & 15, kg = lane >> 4;
    const unsigned short* zrow = Zb6 + ((size_t)(m0 + r16) << 6) + (kg << 3);
    bf16x8 a0 = *(const bf16x8*)zrow;
    bf16x8 a1 = *(const bf16x8*)(zrow + 32);
    f32x4 acc[12];
#pragma unroll
    for (int jt = 0; jt < 12; ++jt) {
        bf16x8 b0 = *(const bf16x8*)(Bfrag + ((size_t)((jt << 1) + 0) << 9) + (lane << 3));
        bf16x8 b1 = *(const bf16x8*)(Bfrag + ((size_t)((jt << 1) + 1) << 9) + (lane << 3));
        f32x4 c = {0.f, 0.f, 0.f, 0.f};
        c = __builtin_amdgcn_mfma_f32_16x16x32_bf16(a0, b0, c, 0, 0, 0);
        c = __builtin_amdgcn_mfma_f32_16x16x32_bf16(a1, b1, c, 0, 0, 0);
        acc[jt] = c;
    }
#pragma unroll
    for (int jt = 0; jt < 12; ++jt) {
        float bi = bih[jt * 16 + r16];
#pragma unroll
        for (int reg = 0; reg < 4; ++reg) {
            int node = m0 + (kg << 2) + reg;
            gi[(size_t)node * 192 + jt * 16 + r16] = f2bf(acc[jt][reg] + bi);
        }
    }
}

// ---- fused 6-step GRU v6: RBG=4 nodes/wave, 4 waves/block (5000 waves) --
__global__ __launch_bounds__(256) void gru6_kernel(
        const unsigned short* __restrict__ gi,
        const unsigned* __restrict__ Wh01, const unsigned short* __restrict__ Whn,
        const float* __restrict__ bhh, float* __restrict__ hfinal) {
    __shared__ unsigned sW01[HH * HH];        // 16 KB
    __shared__ unsigned short sWn[HH * HH];   // 8 KB
    __shared__ float hs[4][RBG][HH];          // 4 KB
    int tid = threadIdx.x;
    int wid = tid >> 6, lane = tid & 63;
    int nbase = (blockIdx.x * 4 + wid) * RBG;

    for (int i = tid; i < HH * HH; i += 256) { sW01[i] = Wh01[i]; sWn[i] = Whn[i]; }
    __syncthreads();

#pragma unroll
    for (int r = 0; r < RBG; ++r) hs[wid][r][lane] = 0.f;
    float bh0 = bhh[lane], bh1 = bhh[64 + lane], bh2 = bhh[128 + lane];

#pragma unroll 1
    for (int t = 0; t < TT; ++t) {
        float aR[RBG], aZ[RBG], aN[RBG];
#pragma unroll
        for (int r = 0; r < RBG; ++r) { aR[r] = aZ[r] = aN[r] = 0.f; }
#pragma unroll 1
        for (int k0 = 0; k0 < 16; ++k0) {
            float4 hv[RBG];
#pragma unroll
            for (int r = 0; r < RBG; ++r) hv[r] = *(const float4*)(&hs[wid][r][k0 << 2]);
#pragma unroll
            for (int u = 0; u < 4; ++u) {
                int k = k0 * 4 + u;
                unsigned w01 = sW01[(k << 6) + lane];
                float w_hr = bflo(w01), w_hz = bfhi(w01);
                float w_hn = bflo((unsigned)sWn[(k << 6) + lane]);
#pragma unroll
                for (int r = 0; r < RBG; ++r) {
                    float hk = (u == 0) ? hv[r].x : (u == 1) ? hv[r].y
                             : (u == 2) ? hv[r].z : hv[r].w;
                    aR[r] = fmaf(hk, w_hr, aR[r]);
                    aZ[r] = fmaf(hk, w_hz, aZ[r]);
                    aN[r] = fmaf(hk, w_hn, aN[r]);
                }
            }
        }
        const unsigned short* gp = gi + ((size_t)t * NN + nbase) * 192;
#pragma unroll
        for (int r = 0; r < RBG; ++r) {
            size_t gb = (size_t)r * 192;
            float gr = bflo((unsigned)gp[gb + lane]);
            float gz = bflo((unsigned)gp[gb + 64 + lane]);
            float gn = bflo((unsigned)gp[gb + 128 + lane]);
            float rr = fsig(gr + aR[r] + bh0);
            float zz = fsig(gz + aZ[r] + bh1);
            float nn_ = ftanh(gn + rr * (aN[r] + bh2));
            hs[wid][r][lane] = (1.f - zz) * nn_ + zz * hs[wid][r][lane];
        }
    }
#pragma unroll
    for (int r = 0; r < RBG; ++r)
        hfinal[((size_t)(nbase + r) << 6) + lane] = hs[wid][r][lane];
}

// ---- fused MLP head: out = sigmoid(relu(h@W3+b3)@W4 + b4) ---------------
__global__ void head_kernel(const float* __restrict__ h, const float* __restrict__ W3,
                            const float* __restrict__ b3, const float* __restrict__ W4,
                            const float* __restrict__ b4, float* __restrict__ out) {
    int nbase = blockIdx.x * RB;
    int lane = threadIdx.x;
    float acc[RB];
#pragma unroll
    for (int r = 0; r < RB; ++r) acc[r] = 0.f;
    for (int k0 = 0; k0 < 16; ++k0) {
        float4 hv[RB];
#pragma unroll
        for (int r = 0; r < RB; ++r)
            hv[r] = ((const float4*)(h + ((size_t)(nbase + r) << 6)))[k0];
#pragma unroll
        for (int u = 0; u < 4; ++u) {
            float w = W3[(k0 * 4 + u) * HH + lane];
#pragma unroll
            for (int r = 0; r < RB; ++r) {
                float hk = (u == 0) ? hv[r].x : (u == 1) ? hv[r].y : (u == 2) ? hv[r].z : hv[r].w;
                acc[r] = fmaf(hk, w, acc[r]);
            }
        }
    }
    float bb = b3[lane], w4 = W4[lane], b40 = b4[0];
#pragma unroll
    for (int r = 0; r < RB; ++r) {
        float v = acc[r] + bb;
        v = v > 0.f ? v : 0.f;
        float s = v * w4;
        s += __shfl_xor(s, 32); s += __shfl_xor(s, 16); s += __shfl_xor(s, 8);
        s += __shfl_xor(s, 4);  s += __shfl_xor(s, 2);  s += __shfl_xor(s, 1);
        if (lane == r) out[nbase + r] = 1.f / (1.f + expf(-(s + b40)));
    }
}

extern "C" void kernel_launch(void* const* d_in, const int* in_sizes, int n_in,
                              void* d_out, int out_size, void* d_ws, size_t ws_size,
                              hipStream_t stream) {
    const float* nf    = (const float*)d_in[0];
    const int*   edges = (const int*)  d_in[1];
    const float* W1  = (const float*)d_in[2];
    const float* b1  = (const float*)d_in[3];
    const float* W2  = (const float*)d_in[4];
    const float* b2  = (const float*)d_in[5];
    const float* wih = (const float*)d_in[6];
    const float* whh = (const float*)d_in[7];
    const float* bih = (const float*)d_in[8];
    const float* bhh = (const float*)d_in[9];
    const float* W3  = (const float*)d_in[10];
    const float* b3  = (const float*)d_in[11];
    const float* W4  = (const float*)d_in[12];
    const float* b4  = (const float*)d_in[13];
    float* out = (float*)d_out;

    // workspace layout
    int* wsi      = (int*)d_ws;
    int* gcur     = wsi;                              // 6*NBKT (zeroed)
    int* gbase    = gcur + 6 * NBKT;                  // 6*NBKT
    int* rowptr6  = gbase + 6 * NBKT;                 // 6*(NN+1)
    int* col6     = rowptr6 + 6 * (NN + 1);           // 6*EE
    int* bucketArr= col6 + (size_t)6 * EE;            // 6*NBKT*CAP
    uintptr_t fbase = ((uintptr_t)(bucketArr + (size_t)6 * NBKT * CAP) + 15) & ~(uintptr_t)15;
    unsigned short* Bfrag = (unsigned short*)fbase;   // 24*64*8 bf16
    unsigned short* Bfrag2= Bfrag + 24 * 64 * 8;      // 8*64*8 bf16
    unsigned* Wh01= (unsigned*)(Bfrag2 + 8 * 64 * 8); // 4096 uint
    unsigned short* Whn = (unsigned short*)(Wh01 + HH * HH);  // 4096 ushort
    float* dinv6 = (float*)(Whn + HH * HH);           // 6*NN
    float* Hf    = dinv6 + 6 * NN;                    // NN*HH (final h, fp32)
    unsigned short* Yb    = (unsigned short*)(Hf + (size_t)NN * HH);  // 6*NN*HH bf16
    unsigned short* Y2all = Yb + (size_t)6 * NN * HH;                 // 6*NN*HH bf16
    unsigned short* Zb1   = Y2all + (size_t)6 * NN * HH;              // 6*NN*HH bf16
    unsigned short* Zb2   = Zb1 + (size_t)6 * NN * HH;                // 6*NN*HH bf16
    unsigned short* gi    = Zb2 + (size_t)6 * NN * HH;                // 6*NN*192 bf16

    const int BS  = 256;
    const int gNH = (NN * HH + BS - 1) / BS;   // 5000
    const int gRB = NN / RB;                   // 2500
    const int gG6 = NN / (RBG * 4);            // 1250 blocks x 4 waves
    const int gMM = (TT * NN) / 64;            // 1875
    const int gBIN = (EE + EPB - 1) / EPB;     // 157

    hipMemsetAsync(gcur, 0, 6 * NBKT * sizeof(int), stream);
    pack_gruh_kernel<<<(HH * HH + BS - 1) / BS, BS, 0, stream>>>(whh, Wh01, Whn);
    pack_bfrag_kernel<<<(24 * 64 * 8 + BS - 1) / BS, BS, 0, stream>>>(wih, Bfrag);
    pack_bfrag2_kernel<<<(8 * 64 * 8 + BS - 1) / BS, BS, 0, stream>>>(W2, Bfrag2);

    bin6_kernel<<<dim3(gBIN, TT), BS, 0, stream>>>(edges, gcur, bucketArr);
    scan_gcur_kernel<<<TT, BS, 0, stream>>>(gcur, gbase, rowptr6);
    regroup6_kernel<<<dim3(NBKT, TT), BS, 0, stream>>>(gcur, gbase, bucketArr,
                                                       rowptr6, dinv6, col6);
    y1all_kernel<<<dim3(gNH, TT), BS, 0, stream>>>(nf, W1, dinv6, Yb);

    // GCN layer 1 (all t) -> dense via MFMA (all t) -> GCN layer 2 (all t)
    gather6_kernel<<<GTOT, BS, 0, stream>>>(rowptr6, col6, dinv6, Yb, b1, Zb1);
    y2all_mfma_kernel<<<gMM, 256, 0, stream>>>(Zb1, Bfrag2, dinv6, Y2all);
    gather6_kernel<<<GTOT, BS, 0, stream>>>(rowptr6, col6, dinv6, Y2all, b2, Zb2);

    // gi = Zb2 @ wihT + bih via MFMA, then sequential h-only GRU
    giall_mfma_kernel<<<gMM, 256, 0, stream>>>(Zb2, Bfrag, bih, gi);
    gru6_kernel<<<gG6, 256, 0, stream>>>(gi, Wh01, Whn, bhh, Hf);

    head_kernel<<<gRB, 64, 0, stream>>>(Hf, W3, b3, W4, b4, out);
}

// Round 25
// 254.831 us; speedup vs baseline: 1.2875x; 1.1520x over previous
//
#include <hip/hip_runtime.h>
#include <math.h>

static constexpr int NN   = 20000;
static constexpr int TT   = 6;
static constexpr int EE   = 640000;
static constexpr int CINC = 3;
static constexpr int HH   = 64;
static constexpr int RB   = 8;    // nodes per wave (head)
static constexpr int RBG  = 4;    // nodes per wave in gru6
static constexpr int BKSH = 7;    // 128 nodes per bucket
static constexpr int NBKT = (NN + (1 << BKSH) - 1) >> BKSH;  // 157
static constexpr int CAP  = 6144; // bucket capacity
static constexpr int EPB  = 4096; // edges per workgroup in bin phase
static constexpr int GBLK = 5000; // gather blocks per timestep (4 nodes each)
static constexpr int GTOT = TT * GBLK;      // 30000
static constexpr int GPX  = GTOT / 8;       // 3750 per XCD
static constexpr int G1NPB = 32;            // gather1x nodes per block
static constexpr int G1BPT = (NN + G1NPB - 1) / G1NPB;  // 625
static constexpr int G1TOT = TT * G1BPT;    // 3750
static constexpr int G1PX  = (G1TOT + 7) / 8;  // 469

typedef __attribute__((ext_vector_type(8))) short bf16x8;
typedef __attribute__((ext_vector_type(4))) float f32x4;

// ---- bf16 helpers --------------------------------------------------------
__device__ inline unsigned short f2bf(float f) {
    unsigned u = __float_as_uint(f);
    unsigned r = (u + 0x7FFFu + ((u >> 16) & 1u)) >> 16;  // RTNE
    return (unsigned short)r;
}
__device__ inline float bflo(unsigned u) { return __uint_as_float(u << 16); }
__device__ inline float bfhi(unsigned u) { return __uint_as_float(u & 0xFFFF0000u); }

// fast transcendentals (gru6 only)
__device__ inline float fsig(float x) {
    return __builtin_amdgcn_rcpf(1.f + __expf(-x));
}
__device__ inline float ftanh(float x) {
    x = fminf(fmaxf(x, -15.f), 15.f);
    float e = __expf(2.f * x);
    return (e - 1.f) * __builtin_amdgcn_rcpf(e + 1.f);
}

// ---- phase 1: bin edges into 157 coarse buckets (packed dstLocal|src) ----
__global__ void bin6_kernel(const int* __restrict__ edges, int* __restrict__ gcur,
                            int* __restrict__ bucketArr) {
    int t = blockIdx.y;
    __shared__ int hist[NBKT];
    __shared__ int base[NBKT];
    int tid = threadIdx.x;
    for (int i = tid; i < NBKT; i += 256) hist[i] = 0;
    __syncthreads();
    const int* src = edges + (size_t)t * 2 * EE;
    const int* dst = src + EE;
    int e0 = blockIdx.x * EPB;
    int pack[16], loff[16], bkt[16];
    int m = 0;
#pragma unroll
    for (int i = 0; i < 16; ++i) {
        int e = e0 + tid + i * 256;
        if (e < EE) {
            int s = src[e], d = dst[e];
            int b = d >> BKSH;
            bkt[i] = b;
            pack[i] = ((d & 127) << 16) | s;
            loff[i] = atomicAdd(&hist[b], 1);
            m = i + 1;
        }
    }
    __syncthreads();
    for (int i = tid; i < NBKT; i += 256)
        base[i] = atomicAdd(&gcur[t * NBKT + i], hist[i]);
    __syncthreads();
    for (int i = 0; i < m; ++i) {
        int b = bkt[i];
        int pos = base[b] + loff[i];
        if (pos < CAP)
            bucketArr[(size_t)(t * NBKT + b) * CAP + pos] = pack[i];
    }
}

// ---- tiny per-t exclusive scan of bucket counts -> bucket edge bases ----
__global__ void scan_gcur_kernel(const int* __restrict__ gcur, int* __restrict__ gbase,
                                 int* __restrict__ rowptr6) {
    int t = blockIdx.x;
    __shared__ int sv[NBKT];
    int tid = threadIdx.x;
    if (tid < NBKT) sv[tid] = gcur[t * NBKT + tid];
    __syncthreads();
    if (tid == 0) {
        int s = 0;
        for (int i = 0; i < NBKT; ++i) { int v = sv[i]; sv[i] = s; s += v; }
        rowptr6[t * (NN + 1) + NN] = EE;
    }
    __syncthreads();
    if (tid < NBKT) gbase[t * NBKT + tid] = sv[tid];
}

// ---- merged: per-bucket hist + scan -> rowptr/dinv/cursor, then regroup --
__global__ void regroup6_kernel(const int* __restrict__ gcur, const int* __restrict__ gbase,
                                const int* __restrict__ bucketArr, int* __restrict__ rowptr6,
                                float* __restrict__ dinv6, int* __restrict__ col6) {
    int bk = blockIdx.x, t = blockIdx.y;
    __shared__ int hist[128];
    __shared__ int lscan[128];
    __shared__ int cursor[128];
    __shared__ int lcol[CAP];  // 24KB
    int tid = threadIdx.x;
    if (tid < 128) hist[tid] = 0;
    __syncthreads();
    int ecnt = gcur[t * NBKT + bk];
    if (ecnt > CAP) ecnt = CAP;
    const int* barr = bucketArr + (size_t)(t * NBKT + bk) * CAP;
    for (int e = tid; e < ecnt; e += 256) atomicAdd(&hist[barr[e] >> 16], 1);
    __syncthreads();
    if (tid < 128) lscan[tid] = hist[tid];
    __syncthreads();
    for (int off = 1; off < 128; off <<= 1) {
        int v = 0, a = 0;
        if (tid < 128) { v = lscan[tid]; a = (tid >= off) ? lscan[tid - off] : 0; }
        __syncthreads();
        if (tid < 128) lscan[tid] = v + a;
        __syncthreads();
    }
    int base = gbase[t * NBKT + bk];
    int nb0 = bk << BKSH;
    if (tid < 128) {
        int excl = lscan[tid] - hist[tid];
        cursor[tid] = excl;
        int n = nb0 + tid;
        if (n < NN) {
            rowptr6[t * (NN + 1) + n] = base + excl;
            dinv6[t * NN + n] = rsqrtf((float)hist[tid] + 1.0f);
        }
    }
    __syncthreads();
    for (int e = tid; e < ecnt; e += 256) {
        int w = barr[e];
        int dl = w >> 16, s = w & 0xFFFF;
        int off = atomicAdd(&cursor[dl], 1);
        lcol[off] = s;
    }
    __syncthreads();
    int* colt = col6 + (size_t)t * EE + base;
    for (int e = tid; e < ecnt; e += 256) colt[e] = lcol[e];
}

// ---- hidden-side GRU weight repack (bf16) for gru6 ----------------------
__global__ void pack_gruh_kernel(const float* __restrict__ whh,
                                 unsigned* __restrict__ Wh01, unsigned short* __restrict__ Whn) {
    int idx = blockIdx.x * blockDim.x + threadIdx.x;  // k*64 + jj
    if (idx >= HH * HH) return;
    int k = idx >> 6, jj = idx & 63;
    unsigned w_hr = f2bf(whh[jj * HH + k]);
    unsigned w_hz = f2bf(whh[(64 + jj) * HH + k]);
    unsigned w_hn = f2bf(whh[(128 + jj) * HH + k]);
    Wh01[idx] = w_hr | (w_hz << 16);
    Whn[idx] = (unsigned short)w_hn;
}

// ---- MFMA B-fragment pack (wih, 24 frags) -------------------------------
__global__ void pack_bfrag_kernel(const float* __restrict__ wih,
                                  unsigned short* __restrict__ Bfrag) {
    int idx = blockIdx.x * blockDim.x + threadIdx.x;
    if (idx >= 24 * 64 * 8) return;
    int frag = idx >> 9;
    int l    = (idx >> 3) & 63;
    int e    = idx & 7;
    int jt = frag >> 1, kk = frag & 1;
    int j = jt * 16 + (l & 15);
    int k = kk * 32 + ((l >> 4) << 3) + e;
    Bfrag[idx] = f2bf(wih[j * HH + k]);
}

// ---- MFMA B-fragment pack (W2, 8 frags): B[k][j] = W2[k*HH+j] -----------
__global__ void pack_bfrag2_kernel(const float* __restrict__ W2,
                                   unsigned short* __restrict__ Bfrag2) {
    int idx = blockIdx.x * blockDim.x + threadIdx.x;
    if (idx >= 8 * 64 * 8) return;
    int frag = idx >> 9;
    int l    = (idx >> 3) & 63;
    int e    = idx & 7;
    int jt = frag >> 1, kk = frag & 1;
    int j = jt * 16 + (l & 15);
    int k = kk * 32 + ((l >> 4) << 3) + e;
    Bfrag2[idx] = f2bf(W2[k * HH + j]);
}

// ---- xd = dinv * x as float4 (for x-space aggregation) ------------------
__global__ void xd_kernel(const float* __restrict__ nf, const float* __restrict__ dinv6,
                          float4* __restrict__ xd6) {
    int t = blockIdx.y;
    int n = blockIdx.x * 256 + threadIdx.x;
    if (n >= NN) return;
    const float* xr = nf + (size_t)t * NN * CINC + n * CINC;
    float d = dinv6[t * NN + n];
    xd6[(size_t)t * NN + n] = make_float4(d * xr[0], d * xr[1], d * xr[2], 0.f);
}

// ---- GCN layer-1 aggregation in 3-dim x-space (linearity of @W1) --------
// agg[d] = dinv[d] * (sum_{s in N(d)} xd[s] + xd[d]); 8 lanes per node.
__global__ void gather1x_kernel(const int* __restrict__ rowptr6, const int* __restrict__ col6,
                                const float* __restrict__ dinv6, const float4* __restrict__ xd6,
                                float4* __restrict__ agg6) {
    int bid = blockIdx.x;
    int widx = (bid & 7) * G1PX + (bid >> 3);
    if (widx >= G1TOT) return;
    int t = widx / G1BPT;
    int iblk = widx - t * G1BPT;
    const int* rowptr = rowptr6 + t * (NN + 1);
    const int* col = col6 + (size_t)t * EE;
    const float4* xd = xd6 + (size_t)t * NN;
    float4* agg = agg6 + (size_t)t * NN;
    const float* dinv = dinv6 + t * NN;
    int tid = threadIdx.x;
    int node = iblk * G1NPB + (tid >> 3);
    if (node >= NN) return;
    int l = tid & 7;
    int ps = rowptr[node], pe = rowptr[node + 1];
    float ax = 0.f, ay = 0.f, az = 0.f;
    for (int p = ps + l; p < pe; p += 8) {
        float4 v = xd[col[p]];
        ax += v.x; ay += v.y; az += v.z;
    }
    ax += __shfl_xor(ax, 1); ay += __shfl_xor(ay, 1); az += __shfl_xor(az, 1);
    ax += __shfl_xor(ax, 2); ay += __shfl_xor(ay, 2); az += __shfl_xor(az, 2);
    ax += __shfl_xor(ax, 4); ay += __shfl_xor(ay, 4); az += __shfl_xor(az, 4);
    if (l == 0) {
        float4 self = xd[node];
        float d = dinv[node];
        agg[node] = make_float4(d * (ax + self.x), d * (ay + self.y),
                                d * (az + self.z), 0.f);
    }
}

// ---- z1 = relu(agg @ W1 + b1), bf16 out ---------------------------------
__global__ void z1_kernel(const float4* __restrict__ agg6, const float* __restrict__ W1,
                          const float* __restrict__ b1, unsigned short* __restrict__ Zb1) {
    int gid = blockIdx.x * 256 + threadIdx.x;   // over TT*NN*HH
    int m = gid >> 6, j = gid & 63;
    if (m >= TT * NN) return;
    float4 a = agg6[m];
    float acc = b1[j];
    acc = fmaf(a.x, W1[0 * HH + j], acc);
    acc = fmaf(a.y, W1[1 * HH + j], acc);
    acc = fmaf(a.z, W1[2 * HH + j], acc);
    Zb1[(size_t)gid] = f2bf(acc > 0.f ? acc : 0.f);
}

// ---- y2 via MFMA: Y2[m][j] = dinv6[m] * (Zb1 @ W2)[m][j] ----------------
__global__ __launch_bounds__(256) void y2all_mfma_kernel(
        const unsigned short* __restrict__ Zb1, const unsigned short* __restrict__ Bfrag2,
        const float* __restrict__ dinv6, unsigned short* __restrict__ Y2all) {
    int w = threadIdx.x >> 6, lane = threadIdx.x & 63;
    int tile = blockIdx.x * 4 + w;
    int m0 = tile << 4;
    int r16 = lane & 15, kg = lane >> 4;
    const unsigned short* zrow = Zb1 + ((size_t)(m0 + r16) << 6) + (kg << 3);
    bf16x8 a0 = *(const bf16x8*)zrow;
    bf16x8 a1 = *(const bf16x8*)(zrow + 32);
    f32x4 acc[4];
#pragma unroll
    for (int jt = 0; jt < 4; ++jt) {
        bf16x8 b0 = *(const bf16x8*)(Bfrag2 + ((size_t)((jt << 1) + 0) << 9) + (lane << 3));
        bf16x8 b1 = *(const bf16x8*)(Bfrag2 + ((size_t)((jt << 1) + 1) << 9) + (lane << 3));
        f32x4 c = {0.f, 0.f, 0.f, 0.f};
        c = __builtin_amdgcn_mfma_f32_16x16x32_bf16(a0, b0, c, 0, 0, 0);
        c = __builtin_amdgcn_mfma_f32_16x16x32_bf16(a1, b1, c, 0, 0, 0);
        acc[jt] = c;
    }
#pragma unroll
    for (int jt = 0; jt < 4; ++jt) {
#pragma unroll
        for (int reg = 0; reg < 4; ++reg) {
            int m = m0 + (kg << 2) + reg;
            Y2all[((size_t)m << 6) + jt * 16 + r16] = f2bf(acc[jt][reg] * dinv6[m]);
        }
    }
}

// ---- CSR gather (layer 2, bf16 rows), balanced XCD partition ------------
__global__ void gather6_kernel(const int* __restrict__ rowptr6, const int* __restrict__ col6,
                               const float* __restrict__ dinv6, const unsigned short* __restrict__ ybase,
                               const float* __restrict__ b, unsigned short* __restrict__ zbase) {
    int bid = blockIdx.x;
    int widx = (bid & 7) * GPX + (bid >> 3);   // balanced, contiguous per XCD
    int t = widx / GBLK;
    int iblk = widx - t * GBLK;
    const int* rowptr = rowptr6 + t * (NN + 1);
    const int* col = col6 + (size_t)t * EE;
    const float* dinv = dinv6 + t * NN;
    const unsigned char* y = (const unsigned char*)(ybase + (size_t)t * NN * HH);
    unsigned short* z = zbase + (size_t)t * NN * HH;

    int node = (iblk * 256 + threadIdx.x) >> 6;
    if (node >= NN) return;
    int lane = threadIdx.x & 63;
    int g = lane >> 3, q = lane & 7;
    int ps = rowptr[node], pe = rowptr[node + 1];
    unsigned qoff = (unsigned)q << 4;
    float acc[8];
    if (g == 0) {  // self term
        const uint4 v = *(const uint4*)(y + (((unsigned)node << 7) + qoff));
        acc[0] = bflo(v.x); acc[1] = bfhi(v.x);
        acc[2] = bflo(v.y); acc[3] = bfhi(v.y);
        acc[4] = bflo(v.z); acc[5] = bfhi(v.z);
        acc[6] = bflo(v.w); acc[7] = bfhi(v.w);
    } else {
#pragma unroll
        for (int j = 0; j < 8; ++j) acc[j] = 0.f;
    }
    for (int p = ps + g; p < pe; p += 8) {
        unsigned c = (unsigned)col[p];
        const uint4 v = *(const uint4*)(y + ((c << 7) + qoff));
        acc[0] += bflo(v.x); acc[1] += bfhi(v.x);
        acc[2] += bflo(v.y); acc[3] += bfhi(v.y);
        acc[4] += bflo(v.z); acc[5] += bfhi(v.z);
        acc[6] += bflo(v.w); acc[7] += bfhi(v.w);
    }
#pragma unroll
    for (int j = 0; j < 8; ++j) {
        acc[j] += __shfl_xor(acc[j], 8);
        acc[j] += __shfl_xor(acc[j], 16);
        acc[j] += __shfl_xor(acc[j], 32);
    }
    if (g == 0) {
        float d = dinv[node];
        const float4 b0 = *(const float4*)(b + (q << 3));
        const float4 b1 = *(const float4*)(b + (q << 3) + 4);
        float o[8];
        o[0] = fmaf(d, acc[0], b0.x); o[1] = fmaf(d, acc[1], b0.y);
        o[2] = fmaf(d, acc[2], b0.z); o[3] = fmaf(d, acc[3], b0.w);
        o[4] = fmaf(d, acc[4], b1.x); o[5] = fmaf(d, acc[5], b1.y);
        o[6] = fmaf(d, acc[6], b1.z); o[7] = fmaf(d, acc[7], b1.w);
#pragma unroll
        for (int j = 0; j < 8; ++j) o[j] = o[j] > 0.f ? o[j] : 0.f;
        uint4 w;
        w.x = (unsigned)f2bf(o[0]) | ((unsigned)f2bf(o[1]) << 16);
        w.y = (unsigned)f2bf(o[2]) | ((unsigned)f2bf(o[3]) << 16);
        w.z = (unsigned)f2bf(o[4]) | ((unsigned)f2bf(o[5]) << 16);
        w.w = (unsigned)f2bf(o[6]) | ((unsigned)f2bf(o[7]) << 16);
        *(uint4*)(z + ((size_t)node << 6) + (q << 3)) = w;
    }
}

// ---- gi via MFMA: gi[m][j] = (Zb2 @ wihT)[m][j] + bih[j] ----------------
__global__ __launch_bounds__(256) void giall_mfma_kernel(
        const unsigned short* __restrict__ Zb6, const unsigned short* __restrict__ Bfrag,
        const float* __restrict__ bih, unsigned short* __restrict__ gi) {
    int w = threadIdx.x >> 6, lane = threadIdx.x & 63;
    int tile = blockIdx.x * 4 + w;
    int m0 = tile << 4;
    int r16 = lane & 15, kg = lane >> 4;
    const unsigned short* zrow = Zb6 + ((size_t)(m0 + r16) << 6) + (kg << 3);
    bf16x8 a0 = *(const bf16x8*)zrow;
    bf16x8 a1 = *(const bf16x8*)(zrow + 32);
    f32x4 acc[12];
#pragma unroll
    for (int jt = 0; jt < 12; ++jt) {
        bf16x8 b0 = *(const bf16x8*)(Bfrag + ((size_t)((jt << 1) + 0) << 9) + (lane << 3));
        bf16x8 b1 = *(const bf16x8*)(Bfrag + ((size_t)((jt << 1) + 1) << 9) + (lane << 3));
        f32x4 c = {0.f, 0.f, 0.f, 0.f};
        c = __builtin_amdgcn_mfma_f32_16x16x32_bf16(a0, b0, c, 0, 0, 0);
        c = __builtin_amdgcn_mfma_f32_16x16x32_bf16(a1, b1, c, 0, 0, 0);
        acc[jt] = c;
    }
#pragma unroll
    for (int jt = 0; jt < 12; ++jt) {
        float bi = bih[jt * 16 + r16];
#pragma unroll
        for (int reg = 0; reg < 4; ++reg) {
            int node = m0 + (kg << 2) + reg;
            gi[(size_t)node * 192 + jt * 16 + r16] = f2bf(acc[jt][reg] + bi);
        }
    }
}

// ---- fused 6-step GRU v6: RBG=4 nodes/wave, 4 waves/block ---------------
__global__ __launch_bounds__(256) void gru6_kernel(
        const unsigned short* __restrict__ gi,
        const unsigned* __restrict__ Wh01, const unsigned short* __restrict__ Whn,
        const float* __restrict__ bhh, float* __restrict__ hfinal) {
    __shared__ unsigned sW01[HH * HH];        // 16 KB
    __shared__ unsigned short sWn[HH * HH];   // 8 KB
    __shared__ float hs[4][RBG][HH];          // 4 KB
    int tid = threadIdx.x;
    int wid = tid >> 6, lane = tid & 63;
    int nbase = (blockIdx.x * 4 + wid) * RBG;

    for (int i = tid; i < HH * HH; i += 256) { sW01[i] = Wh01[i]; sWn[i] = Whn[i]; }
    __syncthreads();

#pragma unroll
    for (int r = 0; r < RBG; ++r) hs[wid][r][lane] = 0.f;
    float bh0 = bhh[lane], bh1 = bhh[64 + lane], bh2 = bhh[128 + lane];

#pragma unroll 1
    for (int t = 0; t < TT; ++t) {
        float aR[RBG], aZ[RBG], aN[RBG];
#pragma unroll
        for (int r = 0; r < RBG; ++r) { aR[r] = aZ[r] = aN[r] = 0.f; }
#pragma unroll 1
        for (int k0 = 0; k0 < 16; ++k0) {
            float4 hv[RBG];
#pragma unroll
            for (int r = 0; r < RBG; ++r) hv[r] = *(const float4*)(&hs[wid][r][k0 << 2]);
#pragma unroll
            for (int u = 0; u < 4; ++u) {
                int k = k0 * 4 + u;
                unsigned w01 = sW01[(k << 6) + lane];
                float w_hr = bflo(w01), w_hz = bfhi(w01);
                float w_hn = bflo((unsigned)sWn[(k << 6) + lane]);
#pragma unroll
                for (int r = 0; r < RBG; ++r) {
                    float hk = (u == 0) ? hv[r].x : (u == 1) ? hv[r].y
                             : (u == 2) ? hv[r].z : hv[r].w;
                    aR[r] = fmaf(hk, w_hr, aR[r]);
                    aZ[r] = fmaf(hk, w_hz, aZ[r]);
                    aN[r] = fmaf(hk, w_hn, aN[r]);
                }
            }
        }
        const unsigned short* gp = gi + ((size_t)t * NN + nbase) * 192;
#pragma unroll
        for (int r = 0; r < RBG; ++r) {
            size_t gb = (size_t)r * 192;
            float gr = bflo((unsigned)gp[gb + lane]);
            float gz = bflo((unsigned)gp[gb + 64 + lane]);
            float gn = bflo((unsigned)gp[gb + 128 + lane]);
            float rr = fsig(gr + aR[r] + bh0);
            float zz = fsig(gz + aZ[r] + bh1);
            float nn_ = ftanh(gn + rr * (aN[r] + bh2));
            hs[wid][r][lane] = (1.f - zz) * nn_ + zz * hs[wid][r][lane];
        }
    }
#pragma unroll
    for (int r = 0; r < RBG; ++r)
        hfinal[((size_t)(nbase + r) << 6) + lane] = hs[wid][r][lane];
}

// ---- fused MLP head: out = sigmoid(relu(h@W3+b3)@W4 + b4) ---------------
__global__ void head_kernel(const float* __restrict__ h, const float* __restrict__ W3,
                            const float* __restrict__ b3, const float* __restrict__ W4,
                            const float* __restrict__ b4, float* __restrict__ out) {
    int nbase = blockIdx.x * RB;
    int lane = threadIdx.x;
    float acc[RB];
#pragma unroll
    for (int r = 0; r < RB; ++r) acc[r] = 0.f;
    for (int k0 = 0; k0 < 16; ++k0) {
        float4 hv[RB];
#pragma unroll
        for (int r = 0; r < RB; ++r)
            hv[r] = ((const float4*)(h + ((size_t)(nbase + r) << 6)))[k0];
#pragma unroll
        for (int u = 0; u < 4; ++u) {
            float w = W3[(k0 * 4 + u) * HH + lane];
#pragma unroll
            for (int r = 0; r < RB; ++r) {
                float hk = (u == 0) ? hv[r].x : (u == 1) ? hv[r].y : (u == 2) ? hv[r].z : hv[r].w;
                acc[r] = fmaf(hk, w, acc[r]);
            }
        }
    }
    float bb = b3[lane], w4 = W4[lane], b40 = b4[0];
#pragma unroll
    for (int r = 0; r < RB; ++r) {
        float v = acc[r] + bb;
        v = v > 0.f ? v : 0.f;
        float s = v * w4;
        s += __shfl_xor(s, 32); s += __shfl_xor(s, 16); s += __shfl_xor(s, 8);
        s += __shfl_xor(s, 4);  s += __shfl_xor(s, 2);  s += __shfl_xor(s, 1);
        if (lane == r) out[nbase + r] = 1.f / (1.f + expf(-(s + b40)));
    }
}

extern "C" void kernel_launch(void* const* d_in, const int* in_sizes, int n_in,
                              void* d_out, int out_size, void* d_ws, size_t ws_size,
                              hipStream_t stream) {
    const float* nf    = (const float*)d_in[0];
    const int*   edges = (const int*)  d_in[1];
    const float* W1  = (const float*)d_in[2];
    const float* b1  = (const float*)d_in[3];
    const float* W2  = (const float*)d_in[4];
    const float* b2  = (const float*)d_in[5];
    const float* wih = (const float*)d_in[6];
    const float* whh = (const float*)d_in[7];
    const float* bih = (const float*)d_in[8];
    const float* bhh = (const float*)d_in[9];
    const float* W3  = (const float*)d_in[10];
    const float* b3  = (const float*)d_in[11];
    const float* W4  = (const float*)d_in[12];
    const float* b4  = (const float*)d_in[13];
    float* out = (float*)d_out;

    // workspace layout
    int* wsi      = (int*)d_ws;
    int* gcur     = wsi;                              // 6*NBKT (zeroed)
    int* gbase    = gcur + 6 * NBKT;                  // 6*NBKT
    int* rowptr6  = gbase + 6 * NBKT;                 // 6*(NN+1)
    int* col6     = rowptr6 + 6 * (NN + 1);           // 6*EE
    int* bucketArr= col6 + (size_t)6 * EE;            // 6*NBKT*CAP
    uintptr_t fbase = ((uintptr_t)(bucketArr + (size_t)6 * NBKT * CAP) + 15) & ~(uintptr_t)15;
    unsigned short* Bfrag = (unsigned short*)fbase;   // 24*64*8 bf16
    unsigned short* Bfrag2= Bfrag + 24 * 64 * 8;      // 8*64*8 bf16
    unsigned* Wh01= (unsigned*)(Bfrag2 + 8 * 64 * 8); // 4096 uint
    unsigned short* Whn = (unsigned short*)(Wh01 + HH * HH);  // 4096 ushort
    float* dinv6 = (float*)(Whn + HH * HH);           // 6*NN
    float* Hf    = dinv6 + 6 * NN;                    // NN*HH (final h, fp32)
    float4* xd6  = (float4*)(Hf + (size_t)NN * HH);   // 6*NN float4
    float4* agg6 = xd6 + (size_t)6 * NN;              // 6*NN float4
    unsigned short* Y2all = (unsigned short*)(agg6 + (size_t)6 * NN);  // 6*NN*HH bf16
    unsigned short* Zb1   = Y2all + (size_t)6 * NN * HH;              // 6*NN*HH bf16
    unsigned short* Zb2   = Zb1 + (size_t)6 * NN * HH;                // 6*NN*HH bf16
    unsigned short* gi    = Zb2 + (size_t)6 * NN * HH;                // 6*NN*192 bf16

    const int BS  = 256;
    const int gN  = (NN + BS - 1) / BS;        // 79
    const int gRB = NN / RB;                   // 2500
    const int gG6 = NN / (RBG * 4);            // 1250
    const int gMM = (TT * NN) / 64;            // 1875
    const int gZ1 = (TT * NN * HH) / BS;       // 30000
    const int gBIN = (EE + EPB - 1) / EPB;     // 157

    hipMemsetAsync(gcur, 0, 6 * NBKT * sizeof(int), stream);
    pack_gruh_kernel<<<(HH * HH + BS - 1) / BS, BS, 0, stream>>>(whh, Wh01, Whn);
    pack_bfrag_kernel<<<(24 * 64 * 8 + BS - 1) / BS, BS, 0, stream>>>(wih, Bfrag);
    pack_bfrag2_kernel<<<(8 * 64 * 8 + BS - 1) / BS, BS, 0, stream>>>(W2, Bfrag2);

    bin6_kernel<<<dim3(gBIN, TT), BS, 0, stream>>>(edges, gcur, bucketArr);
    scan_gcur_kernel<<<TT, BS, 0, stream>>>(gcur, gbase, rowptr6);
    regroup6_kernel<<<dim3(NBKT, TT), BS, 0, stream>>>(gcur, gbase, bucketArr,
                                                       rowptr6, dinv6, col6);

    // GCN layer 1: x-space aggregation (3-dim) then dense @W1
    xd_kernel<<<dim3(gN, TT), BS, 0, stream>>>(nf, dinv6, xd6);
    gather1x_kernel<<<8 * G1PX, BS, 0, stream>>>(rowptr6, col6, dinv6, xd6, agg6);
    z1_kernel<<<gZ1, BS, 0, stream>>>(agg6, W1, b1, Zb1);

    // dense via MFMA -> GCN layer 2 gather
    y2all_mfma_kernel<<<gMM, 256, 0, stream>>>(Zb1, Bfrag2, dinv6, Y2all);
    gather6_kernel<<<GTOT, BS, 0, stream>>>(rowptr6, col6, dinv6, Y2all, b2, Zb2);

    // gi = Zb2 @ wihT + bih via MFMA, then sequential h-only GRU
    giall_mfma_kernel<<<gMM, 256, 0, stream>>>(Zb2, Bfrag, bih, gi);
    gru6_kernel<<<gG6, 256, 0, stream>>>(gi, Wh01, Whn, bhh, Hf);

    head_kernel<<<gRB, 64, 0, stream>>>(Hf, W3, b3, W4, b4, out);
}

// Round 26
// 240.877 us; speedup vs baseline: 1.3620x; 1.0579x over previous
//
#include <hip/hip_runtime.h>
#include <math.h>

static constexpr int NN   = 20000;
static constexpr int TT   = 6;
static constexpr int EE   = 640000;
static constexpr int CINC = 3;
static constexpr int HH   = 64;
static constexpr int RBG  = 4;    // nodes per wave in gru6
static constexpr int BKSH = 7;    // 128 nodes per bucket
static constexpr int NBKT = (NN + (1 << BKSH) - 1) >> BKSH;  // 157
static constexpr int CAP  = 6144; // bucket capacity
static constexpr int EPB  = 4096; // edges per workgroup in bin phase
static constexpr int GBLK = 5000; // gather blocks per timestep (4 nodes each)
static constexpr int GTOT = TT * GBLK;      // 30000
static constexpr int GPX  = GTOT / 8;       // 3750 per XCD
static constexpr int G1NPB = 32;            // gather1x nodes per block
static constexpr int G1BPT = (NN + G1NPB - 1) / G1NPB;  // 625
static constexpr int G1TOT = TT * G1BPT;    // 3750
static constexpr int G1PX  = (G1TOT + 7) / 8;  // 469

typedef __attribute__((ext_vector_type(8))) short bf16x8;
typedef __attribute__((ext_vector_type(4))) float f32x4;

// ---- bf16 helpers --------------------------------------------------------
__device__ inline unsigned short f2bf(float f) {
    unsigned u = __float_as_uint(f);
    unsigned r = (u + 0x7FFFu + ((u >> 16) & 1u)) >> 16;  // RTNE
    return (unsigned short)r;
}
__device__ inline float bflo(unsigned u) { return __uint_as_float(u << 16); }
__device__ inline float bfhi(unsigned u) { return __uint_as_float(u & 0xFFFF0000u); }

// fast transcendentals (gru6 only)
__device__ inline float fsig(float x) {
    return __builtin_amdgcn_rcpf(1.f + __expf(-x));
}
__device__ inline float ftanh(float x) {
    x = fminf(fmaxf(x, -15.f), 15.f);
    float e = __expf(2.f * x);
    return (e - 1.f) * __builtin_amdgcn_rcpf(e + 1.f);
}

// ---- phase 1: bin edges into 157 coarse buckets (packed dstLocal|src) ----
__global__ void bin6_kernel(const int* __restrict__ edges, int* __restrict__ gcur,
                            int* __restrict__ bucketArr) {
    int t = blockIdx.y;
    __shared__ int hist[NBKT];
    __shared__ int base[NBKT];
    int tid = threadIdx.x;
    for (int i = tid; i < NBKT; i += 256) hist[i] = 0;
    __syncthreads();
    const int* src = edges + (size_t)t * 2 * EE;
    const int* dst = src + EE;
    int e0 = blockIdx.x * EPB;
    int pack[16], loff[16], bkt[16];
    int m = 0;
#pragma unroll
    for (int i = 0; i < 16; ++i) {
        int e = e0 + tid + i * 256;
        if (e < EE) {
            int s = src[e], d = dst[e];
            int b = d >> BKSH;
            bkt[i] = b;
            pack[i] = ((d & 127) << 16) | s;
            loff[i] = atomicAdd(&hist[b], 1);
            m = i + 1;
        }
    }
    __syncthreads();
    for (int i = tid; i < NBKT; i += 256)
        base[i] = atomicAdd(&gcur[t * NBKT + i], hist[i]);
    __syncthreads();
    for (int i = 0; i < m; ++i) {
        int b = bkt[i];
        int pos = base[b] + loff[i];
        if (pos < CAP)
            bucketArr[(size_t)(t * NBKT + b) * CAP + pos] = pack[i];
    }
}

// ---- tiny per-t exclusive scan of bucket counts -> bucket edge bases ----
__global__ void scan_gcur_kernel(const int* __restrict__ gcur, int* __restrict__ gbase,
                                 int* __restrict__ rowptr6) {
    int t = blockIdx.x;
    __shared__ int sv[NBKT];
    int tid = threadIdx.x;
    if (tid < NBKT) sv[tid] = gcur[t * NBKT + tid];
    __syncthreads();
    if (tid == 0) {
        int s = 0;
        for (int i = 0; i < NBKT; ++i) { int v = sv[i]; sv[i] = s; s += v; }
        rowptr6[t * (NN + 1) + NN] = EE;
    }
    __syncthreads();
    if (tid < NBKT) gbase[t * NBKT + tid] = sv[tid];
}

// ---- merged: per-bucket hist + scan -> rowptr/dinv/cursor, then regroup --
__global__ void regroup6_kernel(const int* __restrict__ gcur, const int* __restrict__ gbase,
                                const int* __restrict__ bucketArr, int* __restrict__ rowptr6,
                                float* __restrict__ dinv6, int* __restrict__ col6) {
    int bk = blockIdx.x, t = blockIdx.y;
    __shared__ int hist[128];
    __shared__ int lscan[128];
    __shared__ int cursor[128];
    __shared__ int lcol[CAP];  // 24KB
    int tid = threadIdx.x;
    if (tid < 128) hist[tid] = 0;
    __syncthreads();
    int ecnt = gcur[t * NBKT + bk];
    if (ecnt > CAP) ecnt = CAP;
    const int* barr = bucketArr + (size_t)(t * NBKT + bk) * CAP;
    for (int e = tid; e < ecnt; e += 256) atomicAdd(&hist[barr[e] >> 16], 1);
    __syncthreads();
    if (tid < 128) lscan[tid] = hist[tid];
    __syncthreads();
    for (int off = 1; off < 128; off <<= 1) {
        int v = 0, a = 0;
        if (tid < 128) { v = lscan[tid]; a = (tid >= off) ? lscan[tid - off] : 0; }
        __syncthreads();
        if (tid < 128) lscan[tid] = v + a;
        __syncthreads();
    }
    int base = gbase[t * NBKT + bk];
    int nb0 = bk << BKSH;
    if (tid < 128) {
        int excl = lscan[tid] - hist[tid];
        cursor[tid] = excl;
        int n = nb0 + tid;
        if (n < NN) {
            rowptr6[t * (NN + 1) + n] = base + excl;
            dinv6[t * NN + n] = rsqrtf((float)hist[tid] + 1.0f);
        }
    }
    __syncthreads();
    for (int e = tid; e < ecnt; e += 256) {
        int w = barr[e];
        int dl = w >> 16, s = w & 0xFFFF;
        int off = atomicAdd(&cursor[dl], 1);
        lcol[off] = s;
    }
    __syncthreads();
    int* colt = col6 + (size_t)t * EE + base;
    for (int e = tid; e < ecnt; e += 256) colt[e] = lcol[e];
}

// ---- hidden-side GRU weight repack (bf16) for gru6 ----------------------
__global__ void pack_gruh_kernel(const float* __restrict__ whh,
                                 unsigned* __restrict__ Wh01, unsigned short* __restrict__ Whn) {
    int idx = blockIdx.x * blockDim.x + threadIdx.x;  // k*64 + jj
    if (idx >= HH * HH) return;
    int k = idx >> 6, jj = idx & 63;
    unsigned w_hr = f2bf(whh[jj * HH + k]);
    unsigned w_hz = f2bf(whh[(64 + jj) * HH + k]);
    unsigned w_hn = f2bf(whh[(128 + jj) * HH + k]);
    Wh01[idx] = w_hr | (w_hz << 16);
    Whn[idx] = (unsigned short)w_hn;
}

// ---- MFMA B-fragment pack (wih, 24 frags) -------------------------------
__global__ void pack_bfrag_kernel(const float* __restrict__ wih,
                                  unsigned short* __restrict__ Bfrag) {
    int idx = blockIdx.x * blockDim.x + threadIdx.x;
    if (idx >= 24 * 64 * 8) return;
    int frag = idx >> 9;
    int l    = (idx >> 3) & 63;
    int e    = idx & 7;
    int jt = frag >> 1, kk = frag & 1;
    int j = jt * 16 + (l & 15);
    int k = kk * 32 + ((l >> 4) << 3) + e;
    Bfrag[idx] = f2bf(wih[j * HH + k]);
}

// ---- MFMA B-fragment pack (W2, 8 frags): B[k][j] = W2[k*HH+j] -----------
__global__ void pack_bfrag2_kernel(const float* __restrict__ W2,
                                   unsigned short* __restrict__ Bfrag2) {
    int idx = blockIdx.x * blockDim.x + threadIdx.x;
    if (idx >= 8 * 64 * 8) return;
    int frag = idx >> 9;
    int l    = (idx >> 3) & 63;
    int e    = idx & 7;
    int jt = frag >> 1, kk = frag & 1;
    int j = jt * 16 + (l & 15);
    int k = kk * 32 + ((l >> 4) << 3) + e;
    Bfrag2[idx] = f2bf(W2[k * HH + j]);
}

// ---- xd = dinv * x as float4 (for x-space aggregation) ------------------
__global__ void xd_kernel(const float* __restrict__ nf, const float* __restrict__ dinv6,
                          float4* __restrict__ xd6) {
    int t = blockIdx.y;
    int n = blockIdx.x * 256 + threadIdx.x;
    if (n >= NN) return;
    const float* xr = nf + (size_t)t * NN * CINC + n * CINC;
    float d = dinv6[t * NN + n];
    xd6[(size_t)t * NN + n] = make_float4(d * xr[0], d * xr[1], d * xr[2], 0.f);
}

// ---- GCN layer-1 aggregation in 3-dim x-space (linearity of @W1) --------
__global__ void gather1x_kernel(const int* __restrict__ rowptr6, const int* __restrict__ col6,
                                const float* __restrict__ dinv6, const float4* __restrict__ xd6,
                                float4* __restrict__ agg6) {
    int bid = blockIdx.x;
    int widx = (bid & 7) * G1PX + (bid >> 3);
    if (widx >= G1TOT) return;
    int t = widx / G1BPT;
    int iblk = widx - t * G1BPT;
    const int* rowptr = rowptr6 + t * (NN + 1);
    const int* col = col6 + (size_t)t * EE;
    const float4* xd = xd6 + (size_t)t * NN;
    float4* agg = agg6 + (size_t)t * NN;
    const float* dinv = dinv6 + t * NN;
    int tid = threadIdx.x;
    int node = iblk * G1NPB + (tid >> 3);
    if (node >= NN) return;
    int l = tid & 7;
    int ps = rowptr[node], pe = rowptr[node + 1];
    float ax = 0.f, ay = 0.f, az = 0.f;
    for (int p = ps + l; p < pe; p += 8) {
        float4 v = xd[col[p]];
        ax += v.x; ay += v.y; az += v.z;
    }
    ax += __shfl_xor(ax, 1); ay += __shfl_xor(ay, 1); az += __shfl_xor(az, 1);
    ax += __shfl_xor(ax, 2); ay += __shfl_xor(ay, 2); az += __shfl_xor(az, 2);
    ax += __shfl_xor(ax, 4); ay += __shfl_xor(ay, 4); az += __shfl_xor(az, 4);
    if (l == 0) {
        float4 self = xd[node];
        float d = dinv[node];
        agg[node] = make_float4(d * (ax + self.x), d * (ay + self.y),
                                d * (az + self.z), 0.f);
    }
}

// ---- fused z1 + y2 via MFMA: Y2[m][j] = dinv[m]*(relu(agg@W1+b1)@W2)[m][j]
// A-fragments (z1 values) computed on the fly from the 16B agg row.
__global__ __launch_bounds__(256) void y2z1_mfma_kernel(
        const float4* __restrict__ agg6, const float* __restrict__ W1,
        const float* __restrict__ b1, const unsigned short* __restrict__ Bfrag2,
        const float* __restrict__ dinv6, unsigned short* __restrict__ Y2all) {
    int w = threadIdx.x >> 6, lane = threadIdx.x & 63;
    int tile = blockIdx.x * 4 + w;
    int m0 = tile << 4;
    int r16 = lane & 15, kg = lane >> 4;
    float4 a = agg6[m0 + r16];
    bf16x8 a0, a1;
#pragma unroll
    for (int e = 0; e < 8; ++e) {
        int k0 = (kg << 3) + e;          // k in [0,32)
        float v0 = b1[k0];
        v0 = fmaf(a.x, W1[0 * HH + k0], v0);
        v0 = fmaf(a.y, W1[1 * HH + k0], v0);
        v0 = fmaf(a.z, W1[2 * HH + k0], v0);
        a0[e] = (short)f2bf(v0 > 0.f ? v0 : 0.f);
        int k1 = 32 + (kg << 3) + e;     // k in [32,64)
        float v1 = b1[k1];
        v1 = fmaf(a.x, W1[0 * HH + k1], v1);
        v1 = fmaf(a.y, W1[1 * HH + k1], v1);
        v1 = fmaf(a.z, W1[2 * HH + k1], v1);
        a1[e] = (short)f2bf(v1 > 0.f ? v1 : 0.f);
    }
    f32x4 acc[4];
#pragma unroll
    for (int jt = 0; jt < 4; ++jt) {
        bf16x8 b0 = *(const bf16x8*)(Bfrag2 + ((size_t)((jt << 1) + 0) << 9) + (lane << 3));
        bf16x8 b1f = *(const bf16x8*)(Bfrag2 + ((size_t)((jt << 1) + 1) << 9) + (lane << 3));
        f32x4 c = {0.f, 0.f, 0.f, 0.f};
        c = __builtin_amdgcn_mfma_f32_16x16x32_bf16(a0, b0, c, 0, 0, 0);
        c = __builtin_amdgcn_mfma_f32_16x16x32_bf16(a1, b1f, c, 0, 0, 0);
        acc[jt] = c;
    }
#pragma unroll
    for (int jt = 0; jt < 4; ++jt) {
#pragma unroll
        for (int reg = 0; reg < 4; ++reg) {
            int m = m0 + (kg << 2) + reg;
            Y2all[((size_t)m << 6) + jt * 16 + r16] = f2bf(acc[jt][reg] * dinv6[m]);
        }
    }
}

// ---- CSR gather (layer 2, bf16 rows), balanced XCD partition ------------
__global__ void gather6_kernel(const int* __restrict__ rowptr6, const int* __restrict__ col6,
                               const float* __restrict__ dinv6, const unsigned short* __restrict__ ybase,
                               const float* __restrict__ b, unsigned short* __restrict__ zbase) {
    int bid = blockIdx.x;
    int widx = (bid & 7) * GPX + (bid >> 3);   // balanced, contiguous per XCD
    int t = widx / GBLK;
    int iblk = widx - t * GBLK;
    const int* rowptr = rowptr6 + t * (NN + 1);
    const int* col = col6 + (size_t)t * EE;
    const float* dinv = dinv6 + t * NN;
    const unsigned char* y = (const unsigned char*)(ybase + (size_t)t * NN * HH);
    unsigned short* z = zbase + (size_t)t * NN * HH;

    int node = (iblk * 256 + threadIdx.x) >> 6;
    if (node >= NN) return;
    int lane = threadIdx.x & 63;
    int g = lane >> 3, q = lane & 7;
    int ps = rowptr[node], pe = rowptr[node + 1];
    unsigned qoff = (unsigned)q << 4;
    float acc[8];
    if (g == 0) {  // self term
        const uint4 v = *(const uint4*)(y + (((unsigned)node << 7) + qoff));
        acc[0] = bflo(v.x); acc[1] = bfhi(v.x);
        acc[2] = bflo(v.y); acc[3] = bfhi(v.y);
        acc[4] = bflo(v.z); acc[5] = bfhi(v.z);
        acc[6] = bflo(v.w); acc[7] = bfhi(v.w);
    } else {
#pragma unroll
        for (int j = 0; j < 8; ++j) acc[j] = 0.f;
    }
    for (int p = ps + g; p < pe; p += 8) {
        unsigned c = (unsigned)col[p];
        const uint4 v = *(const uint4*)(y + ((c << 7) + qoff));
        acc[0] += bflo(v.x); acc[1] += bfhi(v.x);
        acc[2] += bflo(v.y); acc[3] += bfhi(v.y);
        acc[4] += bflo(v.z); acc[5] += bfhi(v.z);
        acc[6] += bflo(v.w); acc[7] += bfhi(v.w);
    }
#pragma unroll
    for (int j = 0; j < 8; ++j) {
        acc[j] += __shfl_xor(acc[j], 8);
        acc[j] += __shfl_xor(acc[j], 16);
        acc[j] += __shfl_xor(acc[j], 32);
    }
    if (g == 0) {
        float d = dinv[node];
        const float4 b0 = *(const float4*)(b + (q << 3));
        const float4 b1 = *(const float4*)(b + (q << 3) + 4);
        float o[8];
        o[0] = fmaf(d, acc[0], b0.x); o[1] = fmaf(d, acc[1], b0.y);
        o[2] = fmaf(d, acc[2], b0.z); o[3] = fmaf(d, acc[3], b0.w);
        o[4] = fmaf(d, acc[4], b1.x); o[5] = fmaf(d, acc[5], b1.y);
        o[6] = fmaf(d, acc[6], b1.z); o[7] = fmaf(d, acc[7], b1.w);
#pragma unroll
        for (int j = 0; j < 8; ++j) o[j] = o[j] > 0.f ? o[j] : 0.f;
        uint4 w;
        w.x = (unsigned)f2bf(o[0]) | ((unsigned)f2bf(o[1]) << 16);
        w.y = (unsigned)f2bf(o[2]) | ((unsigned)f2bf(o[3]) << 16);
        w.z = (unsigned)f2bf(o[4]) | ((unsigned)f2bf(o[5]) << 16);
        w.w = (unsigned)f2bf(o[6]) | ((unsigned)f2bf(o[7]) << 16);
        *(uint4*)(z + ((size_t)node << 6) + (q << 3)) = w;
    }
}

// ---- gi via MFMA: gi[m][j] = (Zb2 @ wihT)[m][j] + bih[j] ----------------
__global__ __launch_bounds__(256) void giall_mfma_kernel(
        const unsigned short* __restrict__ Zb6, const unsigned short* __restrict__ Bfrag,
        const float* __restrict__ bih, unsigned short* __restrict__ gi) {
    int w = threadIdx.x >> 6, lane = threadIdx.x & 63;
    int tile = blockIdx.x * 4 + w;
    int m0 = tile << 4;
    int r16 = lane & 15, kg = lane >> 4;
    const unsigned short* zrow = Zb6 + ((size_t)(m0 + r16) << 6) + (kg << 3);
    bf16x8 a0 = *(const bf16x8*)zrow;
    bf16x8 a1 = *(const bf16x8*)(zrow + 32);
    f32x4 acc[12];
#pragma unroll
    for (int jt = 0; jt < 12; ++jt) {
        bf16x8 b0 = *(const bf16x8*)(Bfrag + ((size_t)((jt << 1) + 0) << 9) + (lane << 3));
        bf16x8 b1 = *(const bf16x8*)(Bfrag + ((size_t)((jt << 1) + 1) << 9) + (lane << 3));
        f32x4 c = {0.f, 0.f, 0.f, 0.f};
        c = __builtin_amdgcn_mfma_f32_16x16x32_bf16(a0, b0, c, 0, 0, 0);
        c = __builtin_amdgcn_mfma_f32_16x16x32_bf16(a1, b1, c, 0, 0, 0);
        acc[jt] = c;
    }
#pragma unroll
    for (int jt = 0; jt < 12; ++jt) {
        float bi = bih[jt * 16 + r16];
#pragma unroll
        for (int reg = 0; reg < 4; ++reg) {
            int node = m0 + (kg << 2) + reg;
            gi[(size_t)node * 192 + jt * 16 + r16] = f2bf(acc[jt][reg] + bi);
        }
    }
}

// ---- fused 6-step GRU + MLP head: h in LDS; out written directly --------
__global__ __launch_bounds__(256) void gru6_kernel(
        const unsigned short* __restrict__ gi,
        const unsigned* __restrict__ Wh01, const unsigned short* __restrict__ Whn,
        const float* __restrict__ bhh,
        const float* __restrict__ W3, const float* __restrict__ b3,
        const float* __restrict__ W4, const float* __restrict__ b4,
        float* __restrict__ out) {
    __shared__ unsigned sW01[HH * HH];        // 16 KB
    __shared__ unsigned short sWn[HH * HH];   // 8 KB
    __shared__ float hs[4][RBG][HH];          // 4 KB
    int tid = threadIdx.x;
    int wid = tid >> 6, lane = tid & 63;
    int nbase = (blockIdx.x * 4 + wid) * RBG;

    for (int i = tid; i < HH * HH; i += 256) { sW01[i] = Wh01[i]; sWn[i] = Whn[i]; }
    __syncthreads();

#pragma unroll
    for (int r = 0; r < RBG; ++r) hs[wid][r][lane] = 0.f;
    float bh0 = bhh[lane], bh1 = bhh[64 + lane], bh2 = bhh[128 + lane];

#pragma unroll 1
    for (int t = 0; t < TT; ++t) {
        float aR[RBG], aZ[RBG], aN[RBG];
#pragma unroll
        for (int r = 0; r < RBG; ++r) { aR[r] = aZ[r] = aN[r] = 0.f; }
#pragma unroll 1
        for (int k0 = 0; k0 < 16; ++k0) {
            float4 hv[RBG];
#pragma unroll
            for (int r = 0; r < RBG; ++r) hv[r] = *(const float4*)(&hs[wid][r][k0 << 2]);
#pragma unroll
            for (int u = 0; u < 4; ++u) {
                int k = k0 * 4 + u;
                unsigned w01 = sW01[(k << 6) + lane];
                float w_hr = bflo(w01), w_hz = bfhi(w01);
                float w_hn = bflo((unsigned)sWn[(k << 6) + lane]);
#pragma unroll
                for (int r = 0; r < RBG; ++r) {
                    float hk = (u == 0) ? hv[r].x : (u == 1) ? hv[r].y
                             : (u == 2) ? hv[r].z : hv[r].w;
                    aR[r] = fmaf(hk, w_hr, aR[r]);
                    aZ[r] = fmaf(hk, w_hz, aZ[r]);
                    aN[r] = fmaf(hk, w_hn, aN[r]);
                }
            }
        }
        const unsigned short* gp = gi + ((size_t)t * NN + nbase) * 192;
#pragma unroll
        for (int r = 0; r < RBG; ++r) {
            size_t gb = (size_t)r * 192;
            float gr = bflo((unsigned)gp[gb + lane]);
            float gz = bflo((unsigned)gp[gb + 64 + lane]);
            float gn = bflo((unsigned)gp[gb + 128 + lane]);
            float rr = fsig(gr + aR[r] + bh0);
            float zz = fsig(gz + aZ[r] + bh1);
            float nn_ = ftanh(gn + rr * (aN[r] + bh2));
            hs[wid][r][lane] = (1.f - zz) * nn_ + zz * hs[wid][r][lane];
        }
    }
    // ---- fused MLP head: out = sigmoid(relu(h@W3+b3)@W4 + b4) ----
    float acc[RBG];
#pragma unroll
    for (int r = 0; r < RBG; ++r) acc[r] = 0.f;
#pragma unroll 1
    for (int k0 = 0; k0 < 16; ++k0) {
        float4 hv[RBG];
#pragma unroll
        for (int r = 0; r < RBG; ++r) hv[r] = *(const float4*)(&hs[wid][r][k0 << 2]);
#pragma unroll
        for (int u = 0; u < 4; ++u) {
            float w = W3[(k0 * 4 + u) * HH + lane];
#pragma unroll
            for (int r = 0; r < RBG; ++r) {
                float hk = (u == 0) ? hv[r].x : (u == 1) ? hv[r].y
                         : (u == 2) ? hv[r].z : hv[r].w;
                acc[r] = fmaf(hk, w, acc[r]);
            }
        }
    }
    float bb = b3[lane], w4 = W4[lane], b40 = b4[0];
#pragma unroll
    for (int r = 0; r < RBG; ++r) {
        float v = acc[r] + bb;
        v = v > 0.f ? v : 0.f;
        float s = v * w4;
        s += __shfl_xor(s, 32); s += __shfl_xor(s, 16); s += __shfl_xor(s, 8);
        s += __shfl_xor(s, 4);  s += __shfl_xor(s, 2);  s += __shfl_xor(s, 1);
        if (lane == r) out[nbase + r] = 1.f / (1.f + expf(-(s + b40)));
    }
}

extern "C" void kernel_launch(void* const* d_in, const int* in_sizes, int n_in,
                              void* d_out, int out_size, void* d_ws, size_t ws_size,
                              hipStream_t stream) {
    const float* nf    = (const float*)d_in[0];
    const int*   edges = (const int*)  d_in[1];
    const float* W1  = (const float*)d_in[2];
    const float* b1  = (const float*)d_in[3];
    const float* W2  = (const float*)d_in[4];
    const float* b2  = (const float*)d_in[5];
    const float* wih = (const float*)d_in[6];
    const float* whh = (const float*)d_in[7];
    const float* bih = (const float*)d_in[8];
    const float* bhh = (const float*)d_in[9];
    const float* W3  = (const float*)d_in[10];
    const float* b3  = (const float*)d_in[11];
    const float* W4  = (const float*)d_in[12];
    const float* b4  = (const float*)d_in[13];
    float* out = (float*)d_out;

    // workspace layout
    int* wsi      = (int*)d_ws;
    int* gcur     = wsi;                              // 6*NBKT (zeroed)
    int* gbase    = gcur + 6 * NBKT;                  // 6*NBKT
    int* rowptr6  = gbase + 6 * NBKT;                 // 6*(NN+1)
    int* col6     = rowptr6 + 6 * (NN + 1);           // 6*EE
    int* bucketArr= col6 + (size_t)6 * EE;            // 6*NBKT*CAP
    uintptr_t fbase = ((uintptr_t)(bucketArr + (size_t)6 * NBKT * CAP) + 15) & ~(uintptr_t)15;
    unsigned short* Bfrag = (unsigned short*)fbase;   // 24*64*8 bf16
    unsigned short* Bfrag2= Bfrag + 24 * 64 * 8;      // 8*64*8 bf16
    unsigned* Wh01= (unsigned*)(Bfrag2 + 8 * 64 * 8); // 4096 uint
    unsigned short* Whn = (unsigned short*)(Wh01 + HH * HH);  // 4096 ushort
    float* dinv6 = (float*)(Whn + HH * HH);           // 6*NN
    float4* xd6  = (float4*)(dinv6 + 6 * NN + 2);     // 6*NN float4 (16B-align pad)
    float4* agg6 = xd6 + (size_t)6 * NN;              // 6*NN float4
    unsigned short* Y2all = (unsigned short*)(agg6 + (size_t)6 * NN);  // 6*NN*HH bf16
    unsigned short* Zb2   = Y2all + (size_t)6 * NN * HH;              // 6*NN*HH bf16
    unsigned short* gi    = Zb2 + (size_t)6 * NN * HH;                // 6*NN*192 bf16

    const int BS  = 256;
    const int gN  = (NN + BS - 1) / BS;        // 79
    const int gG6 = NN / (RBG * 4);            // 1250
    const int gMM = (TT * NN) / 64;            // 1875
    const int gBIN = (EE + EPB - 1) / EPB;     // 157

    hipMemsetAsync(gcur, 0, 6 * NBKT * sizeof(int), stream);
    pack_gruh_kernel<<<(HH * HH + BS - 1) / BS, BS, 0, stream>>>(whh, Wh01, Whn);
    pack_bfrag_kernel<<<(24 * 64 * 8 + BS - 1) / BS, BS, 0, stream>>>(wih, Bfrag);
    pack_bfrag2_kernel<<<(8 * 64 * 8 + BS - 1) / BS, BS, 0, stream>>>(W2, Bfrag2);

    bin6_kernel<<<dim3(gBIN, TT), BS, 0, stream>>>(edges, gcur, bucketArr);
    scan_gcur_kernel<<<TT, BS, 0, stream>>>(gcur, gbase, rowptr6);
    regroup6_kernel<<<dim3(NBKT, TT), BS, 0, stream>>>(gcur, gbase, bucketArr,
                                                       rowptr6, dinv6, col6);

    // GCN layer 1: x-space aggregation (3-dim), then fused z1+y2 MFMA
    xd_kernel<<<dim3(gN, TT), BS, 0, stream>>>(nf, dinv6, xd6);
    gather1x_kernel<<<8 * G1PX, BS, 0, stream>>>(rowptr6, col6, dinv6, xd6, agg6);
    y2z1_mfma_kernel<<<gMM, 256, 0, stream>>>(agg6, W1, b1, Bfrag2, dinv6, Y2all);

    // GCN layer 2 gather
    gather6_kernel<<<GTOT, BS, 0, stream>>>(rowptr6, col6, dinv6, Y2all, b2, Zb2);

    // gi = Zb2 @ wihT + bih via MFMA, then sequential GRU + fused head
    giall_mfma_kernel<<<gMM, 256, 0, stream>>>(Zb2, Bfrag, bih, gi);
    gru6_kernel<<<gG6, 256, 0, stream>>>(gi, Wh01, Whn, bhh, W3, b3, W4, b4, out);
}

// Round 28
// 207.346 us; speedup vs baseline: 1.5823x; 1.1617x over previous
//
#include <hip/hip_runtime.h>
#include <math.h>

static constexpr int NN   = 20000;
static constexpr int TT   = 6;
static constexpr int EE   = 640000;
static constexpr int CINC = 3;
static constexpr int HH   = 64;
static constexpr int BKSH = 7;    // 128 nodes per bucket
static constexpr int NBKT = (NN + (1 << BKSH) - 1) >> BKSH;  // 157
static constexpr int CAP  = 6144; // bucket capacity
static constexpr int EPB  = 4096; // edges per workgroup in bin phase
static constexpr int GBLK = 5000; // gather blocks per timestep (4 nodes each)
static constexpr int GTOT = TT * GBLK;      // 30000
static constexpr int GPX  = GTOT / 8;       // 3750 per XCD
static constexpr int G1NPB = 32;            // gather1x nodes per block
static constexpr int G1BPT = (NN + G1NPB - 1) / G1NPB;  // 625
static constexpr int G1TOT = TT * G1BPT;    // 3750
static constexpr int G1PX  = (G1TOT + 7) / 8;  // 469

typedef __attribute__((ext_vector_type(8))) short bf16x8;
typedef __attribute__((ext_vector_type(4))) float f32x4;

// ---- bf16 helpers --------------------------------------------------------
__device__ inline unsigned short f2bf(float f) {
    unsigned u = __float_as_uint(f);
    unsigned r = (u + 0x7FFFu + ((u >> 16) & 1u)) >> 16;  // RTNE
    return (unsigned short)r;
}
__device__ inline float bflo(unsigned u) { return __uint_as_float(u << 16); }
__device__ inline float bfhi(unsigned u) { return __uint_as_float(u & 0xFFFF0000u); }

// fast transcendentals (gru6 only)
__device__ inline float fsig(float x) {
    return __builtin_amdgcn_rcpf(1.f + __expf(-x));
}
__device__ inline float ftanh(float x) {
    x = fminf(fmaxf(x, -15.f), 15.f);
    float e = __expf(2.f * x);
    return (e - 1.f) * __builtin_amdgcn_rcpf(e + 1.f);
}

// ---- phase 1: bin edges into 157 coarse buckets (packed dstLocal|src) ----
__global__ void bin6_kernel(const int* __restrict__ edges, int* __restrict__ gcur,
                            int* __restrict__ bucketArr) {
    int t = blockIdx.y;
    __shared__ int hist[NBKT];
    __shared__ int base[NBKT];
    int tid = threadIdx.x;
    for (int i = tid; i < NBKT; i += 256) hist[i] = 0;
    __syncthreads();
    const int* src = edges + (size_t)t * 2 * EE;
    const int* dst = src + EE;
    int e0 = blockIdx.x * EPB;
    int pack[16], loff[16], bkt[16];
    int m = 0;
#pragma unroll
    for (int i = 0; i < 16; ++i) {
        int e = e0 + tid + i * 256;
        if (e < EE) {
            int s = src[e], d = dst[e];
            int b = d >> BKSH;
            bkt[i] = b;
            pack[i] = ((d & 127) << 16) | s;
            loff[i] = atomicAdd(&hist[b], 1);
            m = i + 1;
        }
    }
    __syncthreads();
    for (int i = tid; i < NBKT; i += 256)
        base[i] = atomicAdd(&gcur[t * NBKT + i], hist[i]);
    __syncthreads();
    for (int i = 0; i < m; ++i) {
        int b = bkt[i];
        int pos = base[b] + loff[i];
        if (pos < CAP)
            bucketArr[(size_t)(t * NBKT + b) * CAP + pos] = pack[i];
    }
}

// ---- tiny per-t exclusive scan of bucket counts -> bucket edge bases ----
__global__ void scan_gcur_kernel(const int* __restrict__ gcur, int* __restrict__ gbase,
                                 int* __restrict__ rowptr6) {
    int t = blockIdx.x;
    __shared__ int sv[NBKT];
    int tid = threadIdx.x;
    if (tid < NBKT) sv[tid] = gcur[t * NBKT + tid];
    __syncthreads();
    if (tid == 0) {
        int s = 0;
        for (int i = 0; i < NBKT; ++i) { int v = sv[i]; sv[i] = s; s += v; }
        rowptr6[t * (NN + 1) + NN] = EE;
    }
    __syncthreads();
    if (tid < NBKT) gbase[t * NBKT + tid] = sv[tid];
}

// ---- merged: per-bucket hist + scan -> rowptr/dinv/cursor, then regroup --
__global__ void regroup6_kernel(const int* __restrict__ gcur, const int* __restrict__ gbase,
                                const int* __restrict__ bucketArr, int* __restrict__ rowptr6,
                                float* __restrict__ dinv6, int* __restrict__ col6) {
    int bk = blockIdx.x, t = blockIdx.y;
    __shared__ int hist[128];
    __shared__ int lscan[128];
    __shared__ int cursor[128];
    __shared__ int lcol[CAP];  // 24KB
    int tid = threadIdx.x;
    if (tid < 128) hist[tid] = 0;
    __syncthreads();
    int ecnt = gcur[t * NBKT + bk];
    if (ecnt > CAP) ecnt = CAP;
    const int* barr = bucketArr + (size_t)(t * NBKT + bk) * CAP;
    for (int e = tid; e < ecnt; e += 256) atomicAdd(&hist[barr[e] >> 16], 1);
    __syncthreads();
    if (tid < 128) lscan[tid] = hist[tid];
    __syncthreads();
    for (int off = 1; off < 128; off <<= 1) {
        int v = 0, a = 0;
        if (tid < 128) { v = lscan[tid]; a = (tid >= off) ? lscan[tid - off] : 0; }
        __syncthreads();
        if (tid < 128) lscan[tid] = v + a;
        __syncthreads();
    }
    int base = gbase[t * NBKT + bk];
    int nb0 = bk << BKSH;
    if (tid < 128) {
        int excl = lscan[tid] - hist[tid];
        cursor[tid] = excl;
        int n = nb0 + tid;
        if (n < NN) {
            rowptr6[t * (NN + 1) + n] = base + excl;
            dinv6[t * NN + n] = rsqrtf((float)hist[tid] + 1.0f);
        }
    }
    __syncthreads();
    for (int e = tid; e < ecnt; e += 256) {
        int w = barr[e];
        int dl = w >> 16, s = w & 0xFFFF;
        int off = atomicAdd(&cursor[dl], 1);
        lcol[off] = s;
    }
    __syncthreads();
    int* colt = col6 + (size_t)t * EE + base;
    for (int e = tid; e < ecnt; e += 256) colt[e] = lcol[e];
}

// ---- MFMA B-fragment pack (wih, 24 frags) -------------------------------
__global__ void pack_bfrag_kernel(const float* __restrict__ wih,
                                  unsigned short* __restrict__ Bfrag) {
    int idx = blockIdx.x * blockDim.x + threadIdx.x;
    if (idx >= 24 * 64 * 8) return;
    int frag = idx >> 9;
    int l    = (idx >> 3) & 63;
    int e    = idx & 7;
    int jt = frag >> 1, kk = frag & 1;
    int j = jt * 16 + (l & 15);
    int k = kk * 32 + ((l >> 4) << 3) + e;
    Bfrag[idx] = f2bf(wih[j * HH + k]);
}

// ---- MFMA B-fragment pack (W2, 8 frags): B[k][j] = W2[k*HH+j] -----------
__global__ void pack_bfrag2_kernel(const float* __restrict__ W2,
                                   unsigned short* __restrict__ Bfrag2) {
    int idx = blockIdx.x * blockDim.x + threadIdx.x;
    if (idx >= 8 * 64 * 8) return;
    int frag = idx >> 9;
    int l    = (idx >> 3) & 63;
    int e    = idx & 7;
    int jt = frag >> 1, kk = frag & 1;
    int j = jt * 16 + (l & 15);
    int k = kk * 32 + ((l >> 4) << 3) + e;
    Bfrag2[idx] = f2bf(W2[k * HH + j]);
}

// ---- MFMA B-fragment pack (whh, 24 frags): rows j=0..191 are torch gate rows
__global__ void pack_bfragh_kernel(const float* __restrict__ whh,
                                   unsigned short* __restrict__ Whf) {
    int idx = blockIdx.x * blockDim.x + threadIdx.x;
    if (idx >= 24 * 64 * 8) return;
    int frag = idx >> 9;
    int l    = (idx >> 3) & 63;
    int e    = idx & 7;
    int jt = frag >> 1, kk = frag & 1;
    int j = jt * 16 + (l & 15);
    int k = kk * 32 + ((l >> 4) << 3) + e;
    Whf[idx] = f2bf(whh[j * HH + k]);
}

// ---- MFMA B-fragment pack (W3, 8 frags): B[k][j] = W3[k*HH+j] -----------
__global__ void pack_bfrag3_kernel(const float* __restrict__ W3,
                                   unsigned short* __restrict__ W3f) {
    int idx = blockIdx.x * blockDim.x + threadIdx.x;
    if (idx >= 8 * 64 * 8) return;
    int frag = idx >> 9;
    int l    = (idx >> 3) & 63;
    int e    = idx & 7;
    int jt = frag >> 1, kk = frag & 1;
    int j = jt * 16 + (l & 15);
    int k = kk * 32 + ((l >> 4) << 3) + e;
    W3f[idx] = f2bf(W3[k * HH + j]);
}

// ---- xd = dinv * x as float4 (for x-space aggregation) ------------------
__global__ void xd_kernel(const float* __restrict__ nf, const float* __restrict__ dinv6,
                          float4* __restrict__ xd6) {
    int t = blockIdx.y;
    int n = blockIdx.x * 256 + threadIdx.x;
    if (n >= NN) return;
    const float* xr = nf + (size_t)t * NN * CINC + n * CINC;
    float d = dinv6[t * NN + n];
    xd6[(size_t)t * NN + n] = make_float4(d * xr[0], d * xr[1], d * xr[2], 0.f);
}

// ---- GCN layer-1 aggregation in 3-dim x-space (linearity of @W1) --------
__global__ void gather1x_kernel(const int* __restrict__ rowptr6, const int* __restrict__ col6,
                                const float* __restrict__ dinv6, const float4* __restrict__ xd6,
                                float4* __restrict__ agg6) {
    int bid = blockIdx.x;
    int widx = (bid & 7) * G1PX + (bid >> 3);
    if (widx >= G1TOT) return;
    int t = widx / G1BPT;
    int iblk = widx - t * G1BPT;
    const int* rowptr = rowptr6 + t * (NN + 1);
    const int* col = col6 + (size_t)t * EE;
    const float4* xd = xd6 + (size_t)t * NN;
    float4* agg = agg6 + (size_t)t * NN;
    const float* dinv = dinv6 + t * NN;
    int tid = threadIdx.x;
    int node = iblk * G1NPB + (tid >> 3);
    if (node >= NN) return;
    int l = tid & 7;
    int ps = rowptr[node], pe = rowptr[node + 1];
    float ax = 0.f, ay = 0.f, az = 0.f;
    for (int p = ps + l; p < pe; p += 8) {
        float4 v = xd[col[p]];
        ax += v.x; ay += v.y; az += v.z;
    }
    ax += __shfl_xor(ax, 1); ay += __shfl_xor(ay, 1); az += __shfl_xor(az, 1);
    ax += __shfl_xor(ax, 2); ay += __shfl_xor(ay, 2); az += __shfl_xor(az, 2);
    ax += __shfl_xor(ax, 4); ay += __shfl_xor(ay, 4); az += __shfl_xor(az, 4);
    if (l == 0) {
        float4 self = xd[node];
        float d = dinv[node];
        agg[node] = make_float4(d * (ax + self.x), d * (ay + self.y),
                                d * (az + self.z), 0.f);
    }
}

// ---- fused z1 + y2 via MFMA: Y2[m][j] = dinv[m]*(relu(agg@W1+b1)@W2)[m][j]
__global__ __launch_bounds__(256) void y2z1_mfma_kernel(
        const float4* __restrict__ agg6, const float* __restrict__ W1,
        const float* __restrict__ b1, const unsigned short* __restrict__ Bfrag2,
        const float* __restrict__ dinv6, unsigned short* __restrict__ Y2all) {
    int w = threadIdx.x >> 6, lane = threadIdx.x & 63;
    int tile = blockIdx.x * 4 + w;
    int m0 = tile << 4;
    int r16 = lane & 15, kg = lane >> 4;
    float4 a = agg6[m0 + r16];
    bf16x8 a0, a1;
#pragma unroll
    for (int e = 0; e < 8; ++e) {
        int k0 = (kg << 3) + e;
        float v0 = b1[k0];
        v0 = fmaf(a.x, W1[0 * HH + k0], v0);
        v0 = fmaf(a.y, W1[1 * HH + k0], v0);
        v0 = fmaf(a.z, W1[2 * HH + k0], v0);
        a0[e] = (short)f2bf(v0 > 0.f ? v0 : 0.f);
        int k1 = 32 + (kg << 3) + e;
        float v1 = b1[k1];
        v1 = fmaf(a.x, W1[0 * HH + k1], v1);
        v1 = fmaf(a.y, W1[1 * HH + k1], v1);
        v1 = fmaf(a.z, W1[2 * HH + k1], v1);
        a1[e] = (short)f2bf(v1 > 0.f ? v1 : 0.f);
    }
    f32x4 acc[4];
#pragma unroll
    for (int jt = 0; jt < 4; ++jt) {
        bf16x8 b0 = *(const bf16x8*)(Bfrag2 + ((size_t)((jt << 1) + 0) << 9) + (lane << 3));
        bf16x8 b1f = *(const bf16x8*)(Bfrag2 + ((size_t)((jt << 1) + 1) << 9) + (lane << 3));
        f32x4 c = {0.f, 0.f, 0.f, 0.f};
        c = __builtin_amdgcn_mfma_f32_16x16x32_bf16(a0, b0, c, 0, 0, 0);
        c = __builtin_amdgcn_mfma_f32_16x16x32_bf16(a1, b1f, c, 0, 0, 0);
        acc[jt] = c;
    }
#pragma unroll
    for (int jt = 0; jt < 4; ++jt) {
#pragma unroll
        for (int reg = 0; reg < 4; ++reg) {
            int m = m0 + (kg << 2) + reg;
            Y2all[((size_t)m << 6) + jt * 16 + r16] = f2bf(acc[jt][reg] * dinv6[m]);
        }
    }
}

// ---- CSR gather (layer 2, bf16 rows), balanced XCD partition ------------
__global__ void gather6_kernel(const int* __restrict__ rowptr6, const int* __restrict__ col6,
                               const float* __restrict__ dinv6, const unsigned short* __restrict__ ybase,
                               const float* __restrict__ b, unsigned short* __restrict__ zbase) {
    int bid = blockIdx.x;
    int widx = (bid & 7) * GPX + (bid >> 3);
    int t = widx / GBLK;
    int iblk = widx - t * GBLK;
    const int* rowptr = rowptr6 + t * (NN + 1);
    const int* col = col6 + (size_t)t * EE;
    const float* dinv = dinv6 + t * NN;
    const unsigned char* y = (const unsigned char*)(ybase + (size_t)t * NN * HH);
    unsigned short* z = zbase + (size_t)t * NN * HH;

    int node = (iblk * 256 + threadIdx.x) >> 6;
    if (node >= NN) return;
    int lane = threadIdx.x & 63;
    int g = lane >> 3, q = lane & 7;
    int ps = rowptr[node], pe = rowptr[node + 1];
    unsigned qoff = (unsigned)q << 4;
    float acc[8];
    if (g == 0) {
        const uint4 v = *(const uint4*)(y + (((unsigned)node << 7) + qoff));
        acc[0] = bflo(v.x); acc[1] = bfhi(v.x);
        acc[2] = bflo(v.y); acc[3] = bfhi(v.y);
        acc[4] = bflo(v.z); acc[5] = bfhi(v.z);
        acc[6] = bflo(v.w); acc[7] = bfhi(v.w);
    } else {
#pragma unroll
        for (int j = 0; j < 8; ++j) acc[j] = 0.f;
    }
    for (int p = ps + g; p < pe; p += 8) {
        unsigned c = (unsigned)col[p];
        const uint4 v = *(const uint4*)(y + ((c << 7) + qoff));
        acc[0] += bflo(v.x); acc[1] += bfhi(v.x);
        acc[2] += bflo(v.y); acc[3] += bfhi(v.y);
        acc[4] += bflo(v.z); acc[5] += bfhi(v.z);
        acc[6] += bflo(v.w); acc[7] += bfhi(v.w);
    }
#pragma unroll
    for (int j = 0; j < 8; ++j) {
        acc[j] += __shfl_xor(acc[j], 8);
        acc[j] += __shfl_xor(acc[j], 16);
        acc[j] += __shfl_xor(acc[j], 32);
    }
    if (g == 0) {
        float d = dinv[node];
        const float4 b0 = *(const float4*)(b + (q << 3));
        const float4 b1 = *(const float4*)(b + (q << 3) + 4);
        float o[8];
        o[0] = fmaf(d, acc[0], b0.x); o[1] = fmaf(d, acc[1], b0.y);
        o[2] = fmaf(d, acc[2], b0.z); o[3] = fmaf(d, acc[3], b0.w);
        o[4] = fmaf(d, acc[4], b1.x); o[5] = fmaf(d, acc[5], b1.y);
        o[6] = fmaf(d, acc[6], b1.z); o[7] = fmaf(d, acc[7], b1.w);
#pragma unroll
        for (int j = 0; j < 8; ++j) o[j] = o[j] > 0.f ? o[j] : 0.f;
        uint4 w;
        w.x = (unsigned)f2bf(o[0]) | ((unsigned)f2bf(o[1]) << 16);
        w.y = (unsigned)f2bf(o[2]) | ((unsigned)f2bf(o[3]) << 16);
        w.z = (unsigned)f2bf(o[4]) | ((unsigned)f2bf(o[5]) << 16);
        w.w = (unsigned)f2bf(o[6]) | ((unsigned)f2bf(o[7]) << 16);
        *(uint4*)(z + ((size_t)node << 6) + (q << 3)) = w;
    }
}

// ---- gi via MFMA: gi[m][j] = (Zb2 @ wihT)[m][j] + bih[j] ----------------
__global__ __launch_bounds__(256) void giall_mfma_kernel(
        const unsigned short* __restrict__ Zb6, const unsigned short* __restrict__ Bfrag,
        const float* __restrict__ bih, unsigned short* __restrict__ gi) {
    int w = threadIdx.x >> 6, lane = threadIdx.x & 63;
    int tile = blockIdx.x * 4 + w;
    int m0 = tile << 4;
    int r16 = lane & 15, kg = lane >> 4;
    const unsigned short* zrow = Zb6 + ((size_t)(m0 + r16) << 6) + (kg << 3);
    bf16x8 a0 = *(const bf16x8*)zrow;
    bf16x8 a1 = *(const bf16x8*)(zrow + 32);
    f32x4 acc[12];
#pragma unroll
    for (int jt = 0; jt < 12; ++jt) {
        bf16x8 b0 = *(const bf16x8*)(Bfrag + ((size_t)((jt << 1) + 0) << 9) + (lane << 3));
        bf16x8 b1 = *(const bf16x8*)(Bfrag + ((size_t)((jt << 1) + 1) << 9) + (lane << 3));
        f32x4 c = {0.f, 0.f, 0.f, 0.f};
        c = __builtin_amdgcn_mfma_f32_16x16x32_bf16(a0, b0, c, 0, 0, 0);
        c = __builtin_amdgcn_mfma_f32_16x16x32_bf16(a1, b1, c, 0, 0, 0);
        acc[jt] = c;
    }
#pragma unroll
    for (int jt = 0; jt < 12; ++jt) {
        float bi = bih[jt * 16 + r16];
#pragma unroll
        for (int reg = 0; reg < 4; ++reg) {
            int node = m0 + (kg << 2) + reg;
            gi[(size_t)node * 192 + jt * 16 + r16] = f2bf(acc[jt][reg] + bi);
        }
    }
}

// ---- fused 6-step GRU v7 (MFMA) + MFMA MLP head -------------------------
// one wave per 16 nodes; h in LDS; D layout: row=node=(kg*4+reg), col=j=(l&15)
__global__ __launch_bounds__(64) void gru6_kernel(
        const unsigned short* __restrict__ gi,
        const unsigned short* __restrict__ Whf,
        const float* __restrict__ bhh,
        const unsigned short* __restrict__ W3f, const float* __restrict__ b3,
        const float* __restrict__ W4, const float* __restrict__ b4,
        float* __restrict__ out) {
    __shared__ unsigned short sWhf[24 * 64 * 8];  // 24 KB
    __shared__ float hs[16][HH];                  // 4 KB
    int l = threadIdx.x;
    int nbase = blockIdx.x * 16;
    int r16 = l & 15, kg = l >> 4;

    // cooperative load of whh B-frags (12288 ushorts = 1536 uint4)
    for (int i = l; i < 1536; i += 64)
        ((uint4*)sWhf)[i] = ((const uint4*)Whf)[i];
    for (int i = l; i < 16 * HH; i += 64) ((float*)hs)[i] = 0.f;
    __syncthreads();

    // per-lane gate biases: jj = jt*16 + r16
    float bh0[4], bh1[4], bh2[4];
#pragma unroll
    for (int jt = 0; jt < 4; ++jt) {
        bh0[jt] = bhh[jt * 16 + r16];
        bh1[jt] = bhh[64 + jt * 16 + r16];
        bh2[jt] = bhh[128 + jt * 16 + r16];
    }

#pragma unroll 1
    for (int t = 0; t < TT; ++t) {
        // A-frags from hs: A[row=r16][k = kg*8+e (+32)]
        bf16x8 a0, a1;
#pragma unroll
        for (int e = 0; e < 8; ++e) {
            a0[e] = (short)f2bf(hs[r16][(kg << 3) + e]);
            a1[e] = (short)f2bf(hs[r16][32 + (kg << 3) + e]);
        }
        f32x4 acc[12];
#pragma unroll
        for (int jt = 0; jt < 12; ++jt) {
            bf16x8 b0 = *(const bf16x8*)(sWhf + ((jt << 1) + 0) * 512 + (l << 3));
            bf16x8 b1 = *(const bf16x8*)(sWhf + ((jt << 1) + 1) * 512 + (l << 3));
            f32x4 c = {0.f, 0.f, 0.f, 0.f};
            c = __builtin_amdgcn_mfma_f32_16x16x32_bf16(a0, b0, c, 0, 0, 0);
            c = __builtin_amdgcn_mfma_f32_16x16x32_bf16(a1, b1, c, 0, 0, 0);
            acc[jt] = c;
        }
        __syncthreads();  // all hs reads (A-pack) done before updates below
        // update: lane owns node=(kg*4+reg), jj=jt*16+r16; r/z/n = acc[jt],[jt+4],[jt+8]
#pragma unroll
        for (int reg = 0; reg < 4; ++reg) {
            int nl = (kg << 2) + reg;
            const unsigned short* gp = gi + ((size_t)t * NN + nbase + nl) * 192;
#pragma unroll
            for (int jt = 0; jt < 4; ++jt) {
                int jj = jt * 16 + r16;
                float gr = bflo((unsigned)gp[jj]);
                float gz = bflo((unsigned)gp[64 + jj]);
                float gn = bflo((unsigned)gp[128 + jj]);
                float rr = fsig(gr + acc[jt][reg] + bh0[jt]);
                float zz = fsig(gz + acc[jt + 4][reg] + bh1[jt]);
                float nn_ = ftanh(gn + rr * (acc[jt + 8][reg] + bh2[jt]));
                hs[nl][jj] = (1.f - zz) * nn_ + zz * hs[nl][jj];
            }
        }
        __syncthreads();  // hs fully updated before next t's A-pack
    }

    // ---- MFMA head: hidden = relu(h@W3+b3); out = sigmoid(hidden.W4+b4) --
    bf16x8 a0, a1;
#pragma unroll
    for (int e = 0; e < 8; ++e) {
        a0[e] = (short)f2bf(hs[r16][(kg << 3) + e]);
        a1[e] = (short)f2bf(hs[r16][32 + (kg << 3) + e]);
    }
    f32x4 accH[4];
#pragma unroll
    for (int jt = 0; jt < 4; ++jt) {
        bf16x8 b0 = *(const bf16x8*)(W3f + ((size_t)((jt << 1) + 0) << 9) + (l << 3));
        bf16x8 b1 = *(const bf16x8*)(W3f + ((size_t)((jt << 1) + 1) << 9) + (l << 3));
        f32x4 c = {0.f, 0.f, 0.f, 0.f};
        c = __builtin_amdgcn_mfma_f32_16x16x32_bf16(a0, b0, c, 0, 0, 0);
        c = __builtin_amdgcn_mfma_f32_16x16x32_bf16(a1, b1, c, 0, 0, 0);
        accH[jt] = c;
    }
    // lane partial for node=(kg*4+reg): sum over its 4 j's (jt*16+r16)
    float p[4];
#pragma unroll
    for (int reg = 0; reg < 4; ++reg) {
        float s = 0.f;
#pragma unroll
        for (int jt = 0; jt < 4; ++jt) {
            int j = jt * 16 + r16;
            float v = accH[jt][reg] + b3[j];
            v = v > 0.f ? v : 0.f;
            s = fmaf(v, W4[j], s);
        }
        p[reg] = s;
    }
    // reduce across the 16 lanes (same kg group) holding different r16
#pragma unroll
    for (int reg = 0; reg < 4; ++reg) {
        p[reg] += __shfl_xor(p[reg], 1);
        p[reg] += __shfl_xor(p[reg], 2);
        p[reg] += __shfl_xor(p[reg], 4);
        p[reg] += __shfl_xor(p[reg], 8);
    }
    if (r16 == 0) {
        float b40 = b4[0];
#pragma unroll
        for (int reg = 0; reg < 4; ++reg)
            out[nbase + (kg << 2) + reg] = 1.f / (1.f + expf(-(p[reg] + b40)));
    }
}

extern "C" void kernel_launch(void* const* d_in, const int* in_sizes, int n_in,
                              void* d_out, int out_size, void* d_ws, size_t ws_size,
                              hipStream_t stream) {
    const float* nf    = (const float*)d_in[0];
    const int*   edges = (const int*)  d_in[1];
    const float* W1  = (const float*)d_in[2];
    const float* b1  = (const float*)d_in[3];
    const float* W2  = (const float*)d_in[4];
    const float* b2  = (const float*)d_in[5];
    const float* wih = (const float*)d_in[6];
    const float* whh = (const float*)d_in[7];
    const float* bih = (const float*)d_in[8];
    const float* bhh = (const float*)d_in[9];
    const float* W3  = (const float*)d_in[10];
    const float* b3  = (const float*)d_in[11];
    const float* W4  = (const float*)d_in[12];
    const float* b4  = (const float*)d_in[13];
    float* out = (float*)d_out;

    // workspace layout
    int* wsi      = (int*)d_ws;
    int* gcur     = wsi;                              // 6*NBKT (zeroed)
    int* gbase    = gcur + 6 * NBKT;                  // 6*NBKT
    int* rowptr6  = gbase + 6 * NBKT;                 // 6*(NN+1)
    int* col6     = rowptr6 + 6 * (NN + 1);           // 6*EE
    int* bucketArr= col6 + (size_t)6 * EE;            // 6*NBKT*CAP
    uintptr_t fbase = ((uintptr_t)(bucketArr + (size_t)6 * NBKT * CAP) + 15) & ~(uintptr_t)15;
    unsigned short* Bfrag = (unsigned short*)fbase;   // 24*64*8 bf16 (wih)
    unsigned short* Bfrag2= Bfrag + 24 * 64 * 8;      // 8*64*8 bf16 (W2)
    unsigned short* Whf   = Bfrag2 + 8 * 64 * 8;      // 24*64*8 bf16 (whh)
    unsigned short* W3f   = Whf + 24 * 64 * 8;        // 8*64*8 bf16 (W3)
    float* dinv6 = (float*)(W3f + 8 * 64 * 8);        // 6*NN
    float4* xd6  = (float4*)(dinv6 + 6 * NN + 2);     // 6*NN float4 (16B-align pad)
    float4* agg6 = xd6 + (size_t)6 * NN;              // 6*NN float4
    unsigned short* Y2all = (unsigned short*)(agg6 + (size_t)6 * NN);  // 6*NN*HH bf16
    unsigned short* Zb2   = Y2all + (size_t)6 * NN * HH;              // 6*NN*HH bf16
    unsigned short* gi    = Zb2 + (size_t)6 * NN * HH;                // 6*NN*192 bf16

    const int BS  = 256;
    const int gN  = (NN + BS - 1) / BS;        // 79
    const int gG6 = NN / 16;                   // 1250 one-wave blocks
    const int gMM = (TT * NN) / 64;            // 1875
    const int gBIN = (EE + EPB - 1) / EPB;     // 157

    hipMemsetAsync(gcur, 0, 6 * NBKT * sizeof(int), stream);
    pack_bfrag_kernel<<<(24 * 64 * 8 + BS - 1) / BS, BS, 0, stream>>>(wih, Bfrag);
    pack_bfrag2_kernel<<<(8 * 64 * 8 + BS - 1) / BS, BS, 0, stream>>>(W2, Bfrag2);
    pack_bfragh_kernel<<<(24 * 64 * 8 + BS - 1) / BS, BS, 0, stream>>>(whh, Whf);
    pack_bfrag3_kernel<<<(8 * 64 * 8 + BS - 1) / BS, BS, 0, stream>>>(W3, W3f);

    bin6_kernel<<<dim3(gBIN, TT), BS, 0, stream>>>(edges, gcur, bucketArr);
    scan_gcur_kernel<<<TT, BS, 0, stream>>>(gcur, gbase, rowptr6);
    regroup6_kernel<<<dim3(NBKT, TT), BS, 0, stream>>>(gcur, gbase, bucketArr,
                                                       rowptr6, dinv6, col6);

    // GCN layer 1: x-space aggregation (3-dim), then fused z1+y2 MFMA
    xd_kernel<<<dim3(gN, TT), BS, 0, stream>>>(nf, dinv6, xd6);
    gather1x_kernel<<<8 * G1PX, BS, 0, stream>>>(rowptr6, col6, dinv6, xd6, agg6);
    y2z1_mfma_kernel<<<gMM, 256, 0, stream>>>(agg6, W1, b1, Bfrag2, dinv6, Y2all);

    // GCN layer 2 gather
    gather6_kernel<<<GTOT, BS, 0, stream>>>(rowptr6, col6, dinv6, Y2all, b2, Zb2);

    // gi = Zb2 @ wihT + bih via MFMA, then MFMA GRU + MFMA head
    giall_mfma_kernel<<<gMM, 256, 0, stream>>>(Zb2, Bfrag, bih, gi);
    gru6_kernel<<<gG6, 64, 0, stream>>>(gi, Whf, bhh, W3f, b3, W4, b4, out);
}

// Round 29
// 195.801 us; speedup vs baseline: 1.6756x; 1.0590x over previous
//
#include <hip/hip_runtime.h>
#include <math.h>

static constexpr int NN   = 20000;
static constexpr int TT   = 6;
static constexpr int EE   = 640000;
static constexpr int CINC = 3;
static constexpr int HH   = 64;
static constexpr int BKSH = 7;    // 128 nodes per bucket
static constexpr int NBKT = (NN + (1 << BKSH) - 1) >> BKSH;  // 157
static constexpr int CAP  = 6144; // bucket capacity
static constexpr int EPB  = 4096; // edges per workgroup in bin phase
static constexpr int GBLK = 5000; // gather blocks per timestep (4 nodes each)
static constexpr int GTOT = TT * GBLK;      // 30000
static constexpr int GPX  = GTOT / 8;       // 3750 per XCD
static constexpr int G1NPB = 32;            // gather1x nodes per block
static constexpr int G1BPT = (NN + G1NPB - 1) / G1NPB;  // 625
static constexpr int G1TOT = TT * G1BPT;    // 3750
static constexpr int G1PX  = (G1TOT + 7) / 8;  // 469

typedef __attribute__((ext_vector_type(8))) short bf16x8;
typedef __attribute__((ext_vector_type(4))) float f32x4;

// ---- bf16 helpers --------------------------------------------------------
__device__ inline unsigned short f2bf(float f) {
    unsigned u = __float_as_uint(f);
    unsigned r = (u + 0x7FFFu + ((u >> 16) & 1u)) >> 16;  // RTNE
    return (unsigned short)r;
}
__device__ inline float bflo(unsigned u) { return __uint_as_float(u << 16); }
__device__ inline float bfhi(unsigned u) { return __uint_as_float(u & 0xFFFF0000u); }

// fast transcendentals (gru6 only)
__device__ inline float fsig(float x) {
    return __builtin_amdgcn_rcpf(1.f + __expf(-x));
}
__device__ inline float ftanh(float x) {
    x = fminf(fmaxf(x, -15.f), 15.f);
    float e = __expf(2.f * x);
    return (e - 1.f) * __builtin_amdgcn_rcpf(e + 1.f);
}

// ---- single consolidated pack kernel: zero gcur + 4 weight repacks ------
// segments: [0,942) gcur=0 | [..,+12288) Bfrag(wih) | [+4096) Bfrag2(W2)
//           | [+12288) Whf(whh) | [+4096) W3f(W3)
__global__ void pack_all_kernel(const float* __restrict__ wih, const float* __restrict__ whh,
                                const float* __restrict__ W2, const float* __restrict__ W3,
                                int* __restrict__ gcur,
                                unsigned short* __restrict__ Bfrag,
                                unsigned short* __restrict__ Bfrag2,
                                unsigned short* __restrict__ Whf,
                                unsigned short* __restrict__ W3f) {
    int idx = blockIdx.x * 256 + threadIdx.x;
    if (idx < 6 * NBKT) { gcur[idx] = 0; return; }
    idx -= 6 * NBKT;
    if (idx < 24 * 64 * 8) {
        int frag = idx >> 9, l = (idx >> 3) & 63, e = idx & 7;
        int jt = frag >> 1, kk = frag & 1;
        int j = jt * 16 + (l & 15), k = kk * 32 + ((l >> 4) << 3) + e;
        Bfrag[idx] = f2bf(wih[j * HH + k]);
        return;
    }
    idx -= 24 * 64 * 8;
    if (idx < 8 * 64 * 8) {
        int frag = idx >> 9, l = (idx >> 3) & 63, e = idx & 7;
        int jt = frag >> 1, kk = frag & 1;
        int j = jt * 16 + (l & 15), k = kk * 32 + ((l >> 4) << 3) + e;
        Bfrag2[idx] = f2bf(W2[k * HH + j]);
        return;
    }
    idx -= 8 * 64 * 8;
    if (idx < 24 * 64 * 8) {
        int frag = idx >> 9, l = (idx >> 3) & 63, e = idx & 7;
        int jt = frag >> 1, kk = frag & 1;
        int j = jt * 16 + (l & 15), k = kk * 32 + ((l >> 4) << 3) + e;
        Whf[idx] = f2bf(whh[j * HH + k]);
        return;
    }
    idx -= 24 * 64 * 8;
    if (idx < 8 * 64 * 8) {
        int frag = idx >> 9, l = (idx >> 3) & 63, e = idx & 7;
        int jt = frag >> 1, kk = frag & 1;
        int j = jt * 16 + (l & 15), k = kk * 32 + ((l >> 4) << 3) + e;
        W3f[idx] = f2bf(W3[k * HH + j]);
    }
}
static constexpr int PACK_TOT = 6 * NBKT + 24 * 64 * 8 + 8 * 64 * 8 + 24 * 64 * 8 + 8 * 64 * 8;

// ---- phase 1: bin edges into 157 coarse buckets (packed dstLocal|src) ----
__global__ void bin6_kernel(const int* __restrict__ edges, int* __restrict__ gcur,
                            int* __restrict__ bucketArr) {
    int t = blockIdx.y;
    __shared__ int hist[NBKT];
    __shared__ int base[NBKT];
    int tid = threadIdx.x;
    for (int i = tid; i < NBKT; i += 256) hist[i] = 0;
    __syncthreads();
    const int* src = edges + (size_t)t * 2 * EE;
    const int* dst = src + EE;
    int e0 = blockIdx.x * EPB;
    int pack[16], loff[16], bkt[16];
    int m = 0;
#pragma unroll
    for (int i = 0; i < 16; ++i) {
        int e = e0 + tid + i * 256;
        if (e < EE) {
            int s = src[e], d = dst[e];
            int b = d >> BKSH;
            bkt[i] = b;
            pack[i] = ((d & 127) << 16) | s;
            loff[i] = atomicAdd(&hist[b], 1);
            m = i + 1;
        }
    }
    __syncthreads();
    for (int i = tid; i < NBKT; i += 256)
        base[i] = atomicAdd(&gcur[t * NBKT + i], hist[i]);
    __syncthreads();
    for (int i = 0; i < m; ++i) {
        int b = bkt[i];
        int pos = base[b] + loff[i];
        if (pos < CAP)
            bucketArr[(size_t)(t * NBKT + b) * CAP + pos] = pack[i];
    }
}

// ---- merged: in-block bucket-base scan + hist + scan -> rowptr/dinv, regroup
__global__ void regroup6_kernel(const int* __restrict__ gcur,
                                const int* __restrict__ bucketArr, int* __restrict__ rowptr6,
                                float* __restrict__ dinv6, int* __restrict__ col6) {
    int bk = blockIdx.x, t = blockIdx.y;
    __shared__ int red[256];
    __shared__ int hist[128];
    __shared__ int lscan[128];
    __shared__ int cursor[128];
    __shared__ int lcol[CAP];  // 24KB
    int tid = threadIdx.x;
    // exclusive bucket base = sum of gcur[t][i] for i < bk (tree reduce)
    red[tid] = (tid < bk) ? gcur[t * NBKT + tid] : 0;
    __syncthreads();
    for (int off = 128; off; off >>= 1) {
        if (tid < off) red[tid] += red[tid + off];
        __syncthreads();
    }
    int base = red[0];
    if (bk == NBKT - 1 && tid == 0) rowptr6[t * (NN + 1) + NN] = EE;

    if (tid < 128) hist[tid] = 0;
    __syncthreads();
    int ecnt = gcur[t * NBKT + bk];
    if (ecnt > CAP) ecnt = CAP;
    const int* barr = bucketArr + (size_t)(t * NBKT + bk) * CAP;
    for (int e = tid; e < ecnt; e += 256) atomicAdd(&hist[barr[e] >> 16], 1);
    __syncthreads();
    if (tid < 128) lscan[tid] = hist[tid];
    __syncthreads();
    for (int off = 1; off < 128; off <<= 1) {
        int v = 0, a = 0;
        if (tid < 128) { v = lscan[tid]; a = (tid >= off) ? lscan[tid - off] : 0; }
        __syncthreads();
        if (tid < 128) lscan[tid] = v + a;
        __syncthreads();
    }
    int nb0 = bk << BKSH;
    if (tid < 128) {
        int excl = lscan[tid] - hist[tid];
        cursor[tid] = excl;
        int n = nb0 + tid;
        if (n < NN) {
            rowptr6[t * (NN + 1) + n] = base + excl;
            dinv6[t * NN + n] = rsqrtf((float)hist[tid] + 1.0f);
        }
    }
    __syncthreads();
    for (int e = tid; e < ecnt; e += 256) {
        int w = barr[e];
        int dl = w >> 16, s = w & 0xFFFF;
        int off = atomicAdd(&cursor[dl], 1);
        lcol[off] = s;
    }
    __syncthreads();
    int* colt = col6 + (size_t)t * EE + base;
    for (int e = tid; e < ecnt; e += 256) colt[e] = lcol[e];
}

// ---- xd = dinv * x as float4 (for x-space aggregation) ------------------
__global__ void xd_kernel(const float* __restrict__ nf, const float* __restrict__ dinv6,
                          float4* __restrict__ xd6) {
    int t = blockIdx.y;
    int n = blockIdx.x * 256 + threadIdx.x;
    if (n >= NN) return;
    const float* xr = nf + (size_t)t * NN * CINC + n * CINC;
    float d = dinv6[t * NN + n];
    xd6[(size_t)t * NN + n] = make_float4(d * xr[0], d * xr[1], d * xr[2], 0.f);
}

// ---- GCN layer-1 aggregation in 3-dim x-space (linearity of @W1) --------
__global__ void gather1x_kernel(const int* __restrict__ rowptr6, const int* __restrict__ col6,
                                const float* __restrict__ dinv6, const float4* __restrict__ xd6,
                                float4* __restrict__ agg6) {
    int bid = blockIdx.x;
    int widx = (bid & 7) * G1PX + (bid >> 3);
    if (widx >= G1TOT) return;
    int t = widx / G1BPT;
    int iblk = widx - t * G1BPT;
    const int* rowptr = rowptr6 + t * (NN + 1);
    const int* col = col6 + (size_t)t * EE;
    const float4* xd = xd6 + (size_t)t * NN;
    float4* agg = agg6 + (size_t)t * NN;
    const float* dinv = dinv6 + t * NN;
    int tid = threadIdx.x;
    int node = iblk * G1NPB + (tid >> 3);
    if (node >= NN) return;
    int l = tid & 7;
    int ps = rowptr[node], pe = rowptr[node + 1];
    float ax = 0.f, ay = 0.f, az = 0.f;
    for (int p = ps + l; p < pe; p += 8) {
        float4 v = xd[col[p]];
        ax += v.x; ay += v.y; az += v.z;
    }
    ax += __shfl_xor(ax, 1); ay += __shfl_xor(ay, 1); az += __shfl_xor(az, 1);
    ax += __shfl_xor(ax, 2); ay += __shfl_xor(ay, 2); az += __shfl_xor(az, 2);
    ax += __shfl_xor(ax, 4); ay += __shfl_xor(ay, 4); az += __shfl_xor(az, 4);
    if (l == 0) {
        float4 self = xd[node];
        float d = dinv[node];
        agg[node] = make_float4(d * (ax + self.x), d * (ay + self.y),
                                d * (az + self.z), 0.f);
    }
}

// ---- fused z1 + y2 via MFMA: Y2[m][j] = dinv[m]*(relu(agg@W1+b1)@W2)[m][j]
__global__ __launch_bounds__(256) void y2z1_mfma_kernel(
        const float4* __restrict__ agg6, const float* __restrict__ W1,
        const float* __restrict__ b1, const unsigned short* __restrict__ Bfrag2,
        const float* __restrict__ dinv6, unsigned short* __restrict__ Y2all) {
    int w = threadIdx.x >> 6, lane = threadIdx.x & 63;
    int tile = blockIdx.x * 4 + w;
    int m0 = tile << 4;
    int r16 = lane & 15, kg = lane >> 4;
    float4 a = agg6[m0 + r16];
    bf16x8 a0, a1;
#pragma unroll
    for (int e = 0; e < 8; ++e) {
        int k0 = (kg << 3) + e;
        float v0 = b1[k0];
        v0 = fmaf(a.x, W1[0 * HH + k0], v0);
        v0 = fmaf(a.y, W1[1 * HH + k0], v0);
        v0 = fmaf(a.z, W1[2 * HH + k0], v0);
        a0[e] = (short)f2bf(v0 > 0.f ? v0 : 0.f);
        int k1 = 32 + (kg << 3) + e;
        float v1 = b1[k1];
        v1 = fmaf(a.x, W1[0 * HH + k1], v1);
        v1 = fmaf(a.y, W1[1 * HH + k1], v1);
        v1 = fmaf(a.z, W1[2 * HH + k1], v1);
        a1[e] = (short)f2bf(v1 > 0.f ? v1 : 0.f);
    }
    f32x4 acc[4];
#pragma unroll
    for (int jt = 0; jt < 4; ++jt) {
        bf16x8 b0 = *(const bf16x8*)(Bfrag2 + ((size_t)((jt << 1) + 0) << 9) + (lane << 3));
        bf16x8 b1f = *(const bf16x8*)(Bfrag2 + ((size_t)((jt << 1) + 1) << 9) + (lane << 3));
        f32x4 c = {0.f, 0.f, 0.f, 0.f};
        c = __builtin_amdgcn_mfma_f32_16x16x32_bf16(a0, b0, c, 0, 0, 0);
        c = __builtin_amdgcn_mfma_f32_16x16x32_bf16(a1, b1f, c, 0, 0, 0);
        acc[jt] = c;
    }
#pragma unroll
    for (int jt = 0; jt < 4; ++jt) {
#pragma unroll
        for (int reg = 0; reg < 4; ++reg) {
            int m = m0 + (kg << 2) + reg;
            Y2all[((size_t)m << 6) + jt * 16 + r16] = f2bf(acc[jt][reg] * dinv6[m]);
        }
    }
}

// ---- CSR gather (layer 2, bf16 rows), balanced XCD partition ------------
__global__ void gather6_kernel(const int* __restrict__ rowptr6, const int* __restrict__ col6,
                               const float* __restrict__ dinv6, const unsigned short* __restrict__ ybase,
                               const float* __restrict__ b, unsigned short* __restrict__ zbase) {
    int bid = blockIdx.x;
    int widx = (bid & 7) * GPX + (bid >> 3);
    int t = widx / GBLK;
    int iblk = widx - t * GBLK;
    const int* rowptr = rowptr6 + t * (NN + 1);
    const int* col = col6 + (size_t)t * EE;
    const float* dinv = dinv6 + t * NN;
    const unsigned char* y = (const unsigned char*)(ybase + (size_t)t * NN * HH);
    unsigned short* z = zbase + (size_t)t * NN * HH;

    int node = (iblk * 256 + threadIdx.x) >> 6;
    if (node >= NN) return;
    int lane = threadIdx.x & 63;
    int g = lane >> 3, q = lane & 7;
    int ps = rowptr[node], pe = rowptr[node + 1];
    unsigned qoff = (unsigned)q << 4;
    float acc[8];
    if (g == 0) {
        const uint4 v = *(const uint4*)(y + (((unsigned)node << 7) + qoff));
        acc[0] = bflo(v.x); acc[1] = bfhi(v.x);
        acc[2] = bflo(v.y); acc[3] = bfhi(v.y);
        acc[4] = bflo(v.z); acc[5] = bfhi(v.z);
        acc[6] = bflo(v.w); acc[7] = bfhi(v.w);
    } else {
#pragma unroll
        for (int j = 0; j < 8; ++j) acc[j] = 0.f;
    }
    for (int p = ps + g; p < pe; p += 8) {
        unsigned c = (unsigned)col[p];
        const uint4 v = *(const uint4*)(y + ((c << 7) + qoff));
        acc[0] += bflo(v.x); acc[1] += bfhi(v.x);
        acc[2] += bflo(v.y); acc[3] += bfhi(v.y);
        acc[4] += bflo(v.z); acc[5] += bfhi(v.z);
        acc[6] += bflo(v.w); acc[7] += bfhi(v.w);
    }
#pragma unroll
    for (int j = 0; j < 8; ++j) {
        acc[j] += __shfl_xor(acc[j], 8);
        acc[j] += __shfl_xor(acc[j], 16);
        acc[j] += __shfl_xor(acc[j], 32);
    }
    if (g == 0) {
        float d = dinv[node];
        const float4 b0 = *(const float4*)(b + (q << 3));
        const float4 b1 = *(const float4*)(b + (q << 3) + 4);
        float o[8];
        o[0] = fmaf(d, acc[0], b0.x); o[1] = fmaf(d, acc[1], b0.y);
        o[2] = fmaf(d, acc[2], b0.z); o[3] = fmaf(d, acc[3], b0.w);
        o[4] = fmaf(d, acc[4], b1.x); o[5] = fmaf(d, acc[5], b1.y);
        o[6] = fmaf(d, acc[6], b1.z); o[7] = fmaf(d, acc[7], b1.w);
#pragma unroll
        for (int j = 0; j < 8; ++j) o[j] = o[j] > 0.f ? o[j] : 0.f;
        uint4 w;
        w.x = (unsigned)f2bf(o[0]) | ((unsigned)f2bf(o[1]) << 16);
        w.y = (unsigned)f2bf(o[2]) | ((unsigned)f2bf(o[3]) << 16);
        w.z = (unsigned)f2bf(o[4]) | ((unsigned)f2bf(o[5]) << 16);
        w.w = (unsigned)f2bf(o[6]) | ((unsigned)f2bf(o[7]) << 16);
        *(uint4*)(z + ((size_t)node << 6) + (q << 3)) = w;
    }
}

// ---- gi via MFMA: gi[m][j] = (Zb2 @ wihT)[m][j] + bih[j] ----------------
__global__ __launch_bounds__(256) void giall_mfma_kernel(
        const unsigned short* __restrict__ Zb6, const unsigned short* __restrict__ Bfrag,
        const float* __restrict__ bih, unsigned short* __restrict__ gi) {
    int w = threadIdx.x >> 6, lane = threadIdx.x & 63;
    int tile = blockIdx.x * 4 + w;
    int m0 = tile << 4;
    int r16 = lane & 15, kg = lane >> 4;
    const unsigned short* zrow = Zb6 + ((size_t)(m0 + r16) << 6) + (kg << 3);
    bf16x8 a0 = *(const bf16x8*)zrow;
    bf16x8 a1 = *(const bf16x8*)(zrow + 32);
    f32x4 acc[12];
#pragma unroll
    for (int jt = 0; jt < 12; ++jt) {
        bf16x8 b0 = *(const bf16x8*)(Bfrag + ((size_t)((jt << 1) + 0) << 9) + (lane << 3));
        bf16x8 b1 = *(const bf16x8*)(Bfrag + ((size_t)((jt << 1) + 1) << 9) + (lane << 3));
        f32x4 c = {0.f, 0.f, 0.f, 0.f};
        c = __builtin_amdgcn_mfma_f32_16x16x32_bf16(a0, b0, c, 0, 0, 0);
        c = __builtin_amdgcn_mfma_f32_16x16x32_bf16(a1, b1, c, 0, 0, 0);
        acc[jt] = c;
    }
#pragma unroll
    for (int jt = 0; jt < 12; ++jt) {
        float bi = bih[jt * 16 + r16];
#pragma unroll
        for (int reg = 0; reg < 4; ++reg) {
            int node = m0 + (kg << 2) + reg;
            gi[(size_t)node * 192 + jt * 16 + r16] = f2bf(acc[jt][reg] + bi);
        }
    }
}

// ---- fused 6-step GRU v7 (MFMA) + MFMA MLP head -------------------------
// one wave per 16 nodes; h in LDS; D layout: row=node=(kg*4+reg), col=j=(l&15)
__global__ __launch_bounds__(64) void gru6_kernel(
        const unsigned short* __restrict__ gi,
        const unsigned short* __restrict__ Whf,
        const float* __restrict__ bhh,
        const unsigned short* __restrict__ W3f, const float* __restrict__ b3,
        const float* __restrict__ W4, const float* __restrict__ b4,
        float* __restrict__ out) {
    __shared__ unsigned short sWhf[24 * 64 * 8];  // 24 KB
    __shared__ float hs[16][HH];                  // 4 KB
    int l = threadIdx.x;
    int nbase = blockIdx.x * 16;
    int r16 = l & 15, kg = l >> 4;

    for (int i = l; i < 1536; i += 64)
        ((uint4*)sWhf)[i] = ((const uint4*)Whf)[i];
    for (int i = l; i < 16 * HH; i += 64) ((float*)hs)[i] = 0.f;
    __syncthreads();

    float bh0[4], bh1[4], bh2[4];
#pragma unroll
    for (int jt = 0; jt < 4; ++jt) {
        bh0[jt] = bhh[jt * 16 + r16];
        bh1[jt] = bhh[64 + jt * 16 + r16];
        bh2[jt] = bhh[128 + jt * 16 + r16];
    }

#pragma unroll 1
    for (int t = 0; t < TT; ++t) {
        bf16x8 a0, a1;
#pragma unroll
        for (int e = 0; e < 8; ++e) {
            a0[e] = (short)f2bf(hs[r16][(kg << 3) + e]);
            a1[e] = (short)f2bf(hs[r16][32 + (kg << 3) + e]);
        }
        f32x4 acc[12];
#pragma unroll
        for (int jt = 0; jt < 12; ++jt) {
            bf16x8 b0 = *(const bf16x8*)(sWhf + ((jt << 1) + 0) * 512 + (l << 3));
            bf16x8 b1 = *(const bf16x8*)(sWhf + ((jt << 1) + 1) * 512 + (l << 3));
            f32x4 c = {0.f, 0.f, 0.f, 0.f};
            c = __builtin_amdgcn_mfma_f32_16x16x32_bf16(a0, b0, c, 0, 0, 0);
            c = __builtin_amdgcn_mfma_f32_16x16x32_bf16(a1, b1, c, 0, 0, 0);
            acc[jt] = c;
        }
        __syncthreads();
#pragma unroll
        for (int reg = 0; reg < 4; ++reg) {
            int nl = (kg << 2) + reg;
            const unsigned short* gp = gi + ((size_t)t * NN + nbase + nl) * 192;
#pragma unroll
            for (int jt = 0; jt < 4; ++jt) {
                int jj = jt * 16 + r16;
                float gr = bflo((unsigned)gp[jj]);
                float gz = bflo((unsigned)gp[64 + jj]);
                float gn = bflo((unsigned)gp[128 + jj]);
                float rr = fsig(gr + acc[jt][reg] + bh0[jt]);
                float zz = fsig(gz + acc[jt + 4][reg] + bh1[jt]);
                float nn_ = ftanh(gn + rr * (acc[jt + 8][reg] + bh2[jt]));
                hs[nl][jj] = (1.f - zz) * nn_ + zz * hs[nl][jj];
            }
        }
        __syncthreads();
    }

    // ---- MFMA head: hidden = relu(h@W3+b3); out = sigmoid(hidden.W4+b4) --
    bf16x8 a0, a1;
#pragma unroll
    for (int e = 0; e < 8; ++e) {
        a0[e] = (short)f2bf(hs[r16][(kg << 3) + e]);
        a1[e] = (short)f2bf(hs[r16][32 + (kg << 3) + e]);
    }
    f32x4 accH[4];
#pragma unroll
    for (int jt = 0; jt < 4; ++jt) {
        bf16x8 b0 = *(const bf16x8*)(W3f + ((size_t)((jt << 1) + 0) << 9) + (l << 3));
        bf16x8 b1 = *(const bf16x8*)(W3f + ((size_t)((jt << 1) + 1) << 9) + (l << 3));
        f32x4 c = {0.f, 0.f, 0.f, 0.f};
        c = __builtin_amdgcn_mfma_f32_16x16x32_bf16(a0, b0, c, 0, 0, 0);
        c = __builtin_amdgcn_mfma_f32_16x16x32_bf16(a1, b1, c, 0, 0, 0);
        accH[jt] = c;
    }
    float p[4];
#pragma unroll
    for (int reg = 0; reg < 4; ++reg) {
        float s = 0.f;
#pragma unroll
        for (int jt = 0; jt < 4; ++jt) {
            int j = jt * 16 + r16;
            float v = accH[jt][reg] + b3[j];
            v = v > 0.f ? v : 0.f;
            s = fmaf(v, W4[j], s);
        }
        p[reg] = s;
    }
#pragma unroll
    for (int reg = 0; reg < 4; ++reg) {
        p[reg] += __shfl_xor(p[reg], 1);
        p[reg] += __shfl_xor(p[reg], 2);
        p[reg] += __shfl_xor(p[reg], 4);
        p[reg] += __shfl_xor(p[reg], 8);
    }
    if (r16 == 0) {
        float b40 = b4[0];
#pragma unroll
        for (int reg = 0; reg < 4; ++reg)
            out[nbase + (kg << 2) + reg] = 1.f / (1.f + expf(-(p[reg] + b40)));
    }
}

extern "C" void kernel_launch(void* const* d_in, const int* in_sizes, int n_in,
                              void* d_out, int out_size, void* d_ws, size_t ws_size,
                              hipStream_t stream) {
    const float* nf    = (const float*)d_in[0];
    const int*   edges = (const int*)  d_in[1];
    const float* W1  = (const float*)d_in[2];
    const float* b1  = (const float*)d_in[3];
    const float* W2  = (const float*)d_in[4];
    const float* b2  = (const float*)d_in[5];
    const float* wih = (const float*)d_in[6];
    const float* whh = (const float*)d_in[7];
    const float* bih = (const float*)d_in[8];
    const float* bhh = (const float*)d_in[9];
    const float* W3  = (const float*)d_in[10];
    const float* b3  = (const float*)d_in[11];
    const float* W4  = (const float*)d_in[12];
    const float* b4  = (const float*)d_in[13];
    float* out = (float*)d_out;

    // workspace layout
    int* wsi      = (int*)d_ws;
    int* gcur     = wsi;                              // 6*NBKT (zeroed by pack_all)
    int* rowptr6  = gcur + 6 * NBKT;                  // 6*(NN+1)
    int* col6     = rowptr6 + 6 * (NN + 1);           // 6*EE
    int* bucketArr= col6 + (size_t)6 * EE;            // 6*NBKT*CAP
    uintptr_t fbase = ((uintptr_t)(bucketArr + (size_t)6 * NBKT * CAP) + 15) & ~(uintptr_t)15;
    unsigned short* Bfrag = (unsigned short*)fbase;   // 24*64*8 bf16 (wih)
    unsigned short* Bfrag2= Bfrag + 24 * 64 * 8;      // 8*64*8 bf16 (W2)
    unsigned short* Whf   = Bfrag2 + 8 * 64 * 8;      // 24*64*8 bf16 (whh)
    unsigned short* W3f   = Whf + 24 * 64 * 8;        // 8*64*8 bf16 (W3)
    float* dinv6 = (float*)(W3f + 8 * 64 * 8);        // 6*NN
    float4* xd6  = (float4*)(dinv6 + 6 * NN + 2);     // 6*NN float4 (16B-align pad)
    float4* agg6 = xd6 + (size_t)6 * NN;              // 6*NN float4
    unsigned short* Y2all = (unsigned short*)(agg6 + (size_t)6 * NN);  // 6*NN*HH bf16
    unsigned short* Zb2   = Y2all + (size_t)6 * NN * HH;              // 6*NN*HH bf16
    unsigned short* gi    = Zb2 + (size_t)6 * NN * HH;                // 6*NN*192 bf16

    const int BS  = 256;
    const int gN  = (NN + BS - 1) / BS;        // 79
    const int gG6 = NN / 16;                   // 1250 one-wave blocks
    const int gMM = (TT * NN) / 64;            // 1875
    const int gBIN = (EE + EPB - 1) / EPB;     // 157
    const int gPK = (PACK_TOT + BS - 1) / BS;  // 133

    pack_all_kernel<<<gPK, BS, 0, stream>>>(wih, whh, W2, W3, gcur,
                                            Bfrag, Bfrag2, Whf, W3f);

    bin6_kernel<<<dim3(gBIN, TT), BS, 0, stream>>>(edges, gcur, bucketArr);
    regroup6_kernel<<<dim3(NBKT, TT), BS, 0, stream>>>(gcur, bucketArr,
                                                       rowptr6, dinv6, col6);

    // GCN layer 1: x-space aggregation (3-dim), then fused z1+y2 MFMA
    xd_kernel<<<dim3(gN, TT), BS, 0, stream>>>(nf, dinv6, xd6);
    gather1x_kernel<<<8 * G1PX, BS, 0, stream>>>(rowptr6, col6, dinv6, xd6, agg6);
    y2z1_mfma_kernel<<<gMM, 256, 0, stream>>>(agg6, W1, b1, Bfrag2, dinv6, Y2all);

    // GCN layer 2 gather
    gather6_kernel<<<GTOT, BS, 0, stream>>>(rowptr6, col6, dinv6, Y2all, b2, Zb2);

    // gi = Zb2 @ wihT + bih via MFMA, then MFMA GRU + MFMA head
    giall_mfma_kernel<<<gMM, 256, 0, stream>>>(Zb2, Bfrag, bih, gi);
    gru6_kernel<<<gG6, 64, 0, stream>>>(gi, Whf, bhh, W3f, b3, W4, b4, out);
}